// Round 1
// baseline (2328.776 us; speedup 1.0000x reference)
//
#include <hip/hip_runtime.h>

#define NN   200000
#define EE   6400000
#define INC  128
#define HIDC 16
#define OUTC 2

// ---------------- degree histogram (self-loop added later as +1) ----------
__global__ void k_deg(const int* __restrict__ dst, int* __restrict__ deg) {
    int i = blockIdx.x * blockDim.x + threadIdx.x;
    if (i < EE) atomicAdd(&deg[dst[i]], 1);
}

__global__ void k_dinv(const int* __restrict__ deg, float* __restrict__ dinv) {
    int n = blockIdx.x * blockDim.x + threadIdx.x;
    if (n < NN) dinv[n] = rsqrtf((float)(deg[n] + 1));   // +1 = self-loop
}

// ---------------- g1 = dinv * (x @ W1) ------------------------------------
__global__ __launch_bounds__(256) void k_xw(const float* __restrict__ x,
                                            const float* __restrict__ W1,
                                            const float* __restrict__ dinv,
                                            float* __restrict__ g1) {
    __shared__ float Ws[INC * HIDC];           // 8 KB
    for (int j = threadIdx.x; j < INC * HIDC; j += 256) Ws[j] = W1[j];
    __syncthreads();
    int n = blockIdx.x * 256 + threadIdx.x;
    if (n >= NN) return;
    const float4* xr = (const float4*)(x + (size_t)n * INC);
    float acc[HIDC];
#pragma unroll
    for (int c = 0; c < HIDC; ++c) acc[c] = 0.f;
    for (int k4 = 0; k4 < INC / 4; ++k4) {
        float4 xv = xr[k4];
        const float* w0 = &Ws[(k4 * 4) * HIDC];
        float xs[4] = {xv.x, xv.y, xv.z, xv.w};
#pragma unroll
        for (int j = 0; j < 4; ++j) {
#pragma unroll
            for (int c = 0; c < HIDC; ++c) acc[c] += xs[j] * w0[j * HIDC + c];
        }
    }
    float dn = dinv[n];
    float4* gout = (float4*)(g1 + (size_t)n * HIDC);
#pragma unroll
    for (int q = 0; q < 4; ++q) {
        float4 v;
        v.x = dn * acc[q * 4 + 0];
        v.y = dn * acc[q * 4 + 1];
        v.z = dn * acc[q * 4 + 2];
        v.w = dn * acc[q * 4 + 3];
        gout[q] = v;
    }
}

// ---------------- layer-1 edge scatter: acc1[d] += g1[s] -------------------
// 4 threads per edge, one float4 quarter-row each.
__global__ void k_scatter1(const int* __restrict__ src, const int* __restrict__ dst,
                           const float* __restrict__ g1, float* __restrict__ acc1) {
    int i = blockIdx.x * blockDim.x + threadIdx.x;
    if (i >= EE * 4) return;
    int e = i >> 2, q = i & 3;
    int s = src[e], d = dst[e];
    float4 v = ((const float4*)g1)[s * 4 + q];
    float* p = acc1 + (size_t)d * HIDC + q * 4;
    unsafeAtomicAdd(p + 0, v.x);
    unsafeAtomicAdd(p + 1, v.y);
    unsafeAtomicAdd(p + 2, v.z);
    unsafeAtomicAdd(p + 3, v.w);
}

// ------- epilogue1 + relu + W2 transform + pre-scale for layer 2 -----------
// g2[n] = dinv[n] * ( relu( dinv[n]*(acc1[n]+g1[n]) + b1 ) @ W2 )
__global__ void k_l2(const float* __restrict__ g1, const float* __restrict__ acc1,
                     const float* __restrict__ dinv, const float* __restrict__ b1,
                     const float* __restrict__ W2, float* __restrict__ g2) {
    int n = blockIdx.x * blockDim.x + threadIdx.x;
    if (n >= NN) return;
    float dn = dinv[n];
    const float4* a4 = (const float4*)(acc1 + (size_t)n * HIDC);
    const float4* g4 = (const float4*)(g1 + (size_t)n * HIDC);
    float h[HIDC];
#pragma unroll
    for (int q = 0; q < 4; ++q) {
        float4 a = a4[q], g = g4[q];
        h[q * 4 + 0] = fmaxf(dn * (a.x + g.x) + b1[q * 4 + 0], 0.f);
        h[q * 4 + 1] = fmaxf(dn * (a.y + g.y) + b1[q * 4 + 1], 0.f);
        h[q * 4 + 2] = fmaxf(dn * (a.z + g.z) + b1[q * 4 + 2], 0.f);
        h[q * 4 + 3] = fmaxf(dn * (a.w + g.w) + b1[q * 4 + 3], 0.f);
    }
    float o0 = 0.f, o1 = 0.f;
#pragma unroll
    for (int c = 0; c < HIDC; ++c) {
        o0 += h[c] * W2[c * OUTC + 0];
        o1 += h[c] * W2[c * OUTC + 1];
    }
    g2[(size_t)n * OUTC + 0] = dn * o0;
    g2[(size_t)n * OUTC + 1] = dn * o1;
}

// ---------------- layer-2 edge scatter: acc2[d] += g2[s] -------------------
__global__ void k_scatter2(const int* __restrict__ src, const int* __restrict__ dst,
                           const float* __restrict__ g2, float* __restrict__ acc2) {
    int e = blockIdx.x * blockDim.x + threadIdx.x;
    if (e >= EE) return;
    int s = src[e], d = dst[e];
    float2 v = ((const float2*)g2)[s];
    unsafeAtomicAdd(&acc2[(size_t)d * OUTC + 0], v.x);
    unsafeAtomicAdd(&acc2[(size_t)d * OUTC + 1], v.y);
}

// ---------------- final epilogue -------------------------------------------
__global__ void k_final(const float* __restrict__ g2, const float* __restrict__ acc2,
                        const float* __restrict__ dinv, const float* __restrict__ b2,
                        float* __restrict__ out) {
    int n = blockIdx.x * blockDim.x + threadIdx.x;
    if (n >= NN) return;
    float dn = dinv[n];
    float2 a = ((const float2*)acc2)[n];
    float2 g = ((const float2*)g2)[n];
    float2 o;
    o.x = dn * (a.x + g.x) + b2[0];
    o.y = dn * (a.y + g.y) + b2[1];
    ((float2*)out)[n] = o;
}

extern "C" void kernel_launch(void* const* d_in, const int* in_sizes, int n_in,
                              void* d_out, int out_size, void* d_ws, size_t ws_size,
                              hipStream_t stream) {
    const float* x  = (const float*)d_in[0];
    const int*   ei = (const int*)d_in[1];     // [2, E] flat: src then dst
    const float* W1 = (const float*)d_in[2];
    const float* b1 = (const float*)d_in[3];
    const float* W2 = (const float*)d_in[4];
    const float* b2 = (const float*)d_in[5];
    float* out = (float*)d_out;

    const int* src = ei;
    const int* dst = ei + EE;

    // workspace layout (4-byte elements):
    //   [0,       N)      deg (int)       \
    //   [N,       17N)    acc1 (N*16)      |-- zeroed by one memset
    //   [17N,     19N)    acc2 (N*2)      /
    //   [19N,     20N)    dinv
    //   [20N,     36N)    g1 (N*16)
    //   [36N,     38N)    g2 (N*2)
    char* ws = (char*)d_ws;
    int*   deg  = (int*)ws;
    float* acc1 = (float*)(ws + (size_t)NN * 4);
    float* acc2 = (float*)(ws + (size_t)17 * NN * 4);
    float* dinv = (float*)(ws + (size_t)19 * NN * 4);
    float* g1   = (float*)(ws + (size_t)20 * NN * 4);
    float* g2   = (float*)(ws + (size_t)36 * NN * 4);

    hipMemsetAsync(d_ws, 0, (size_t)19 * NN * 4, stream);

    const int B = 256;
    int gN = (NN + B - 1) / B;
    int gE = (EE + B - 1) / B;
    int gE4 = (EE * 4 + B - 1) / B;

    k_deg<<<gE, B, 0, stream>>>(dst, deg);
    k_dinv<<<gN, B, 0, stream>>>(deg, dinv);
    k_xw<<<gN, B, 0, stream>>>(x, W1, dinv, g1);
    k_scatter1<<<gE4, B, 0, stream>>>(src, dst, g1, acc1);
    k_l2<<<gN, B, 0, stream>>>(g1, acc1, dinv, b1, W2, g2);
    k_scatter2<<<gE, B, 0, stream>>>(src, dst, g2, acc2);
    k_final<<<gN, B, 0, stream>>>(g2, acc2, dinv, b2, out);
}

// Round 2
// 1183.960 us; speedup vs baseline: 1.9669x; 1.9669x over previous
//
#include <hip/hip_runtime.h>

#define NN   200000
#define EE   6400000
#define INC  128
#define HIDC 16
#define OUTC 2

// ======================= shared kernels =====================================

__global__ void k_deg(const int* __restrict__ dst, int* __restrict__ deg) {
    int i = blockIdx.x * blockDim.x + threadIdx.x;
    if (i < EE) atomicAdd(&deg[dst[i]], 1);
}

__global__ void k_dinv(const int* __restrict__ deg, float* __restrict__ dinv) {
    int n = blockIdx.x * blockDim.x + threadIdx.x;
    if (n < NN) dinv[n] = rsqrtf((float)(deg[n] + 1));   // +1 = self-loop
}

// g1 = dinv * (x @ W1)
__global__ __launch_bounds__(256) void k_xw(const float* __restrict__ x,
                                            const float* __restrict__ W1,
                                            const float* __restrict__ dinv,
                                            float* __restrict__ g1) {
    __shared__ float Ws[INC * HIDC];           // 8 KB
    for (int j = threadIdx.x; j < INC * HIDC; j += 256) Ws[j] = W1[j];
    __syncthreads();
    int n = blockIdx.x * 256 + threadIdx.x;
    if (n >= NN) return;
    const float4* xr = (const float4*)(x + (size_t)n * INC);
    float acc[HIDC];
#pragma unroll
    for (int c = 0; c < HIDC; ++c) acc[c] = 0.f;
    for (int k4 = 0; k4 < INC / 4; ++k4) {
        float4 xv = xr[k4];
        const float* w0 = &Ws[(k4 * 4) * HIDC];
        float xs[4] = {xv.x, xv.y, xv.z, xv.w};
#pragma unroll
        for (int j = 0; j < 4; ++j) {
#pragma unroll
            for (int c = 0; c < HIDC; ++c) acc[c] += xs[j] * w0[j * HIDC + c];
        }
    }
    float dn = dinv[n];
    float4* gout = (float4*)(g1 + (size_t)n * HIDC);
#pragma unroll
    for (int q = 0; q < 4; ++q) {
        float4 v;
        v.x = dn * acc[q * 4 + 0];
        v.y = dn * acc[q * 4 + 1];
        v.z = dn * acc[q * 4 + 2];
        v.w = dn * acc[q * 4 + 3];
        gout[q] = v;
    }
}

// ======================= CSR build (counting sort by dst) ===================

// Exclusive scan of deg with non-deterministic block-base placement:
// block total via one atomicAdd on a global counter; segment order is
// irrelevant because the final per-node sum is order-independent.
__global__ __launch_bounds__(256) void k_scan(const int* __restrict__ deg,
                                              int* __restrict__ cursor,
                                              int* __restrict__ counter) {
    __shared__ int tmp[256];
    __shared__ int base_s;
    int n = blockIdx.x * 256 + threadIdx.x;
    int v = (n < NN) ? deg[n] : 0;
    tmp[threadIdx.x] = v;
    __syncthreads();
    for (int o = 1; o < 256; o <<= 1) {
        int t = (threadIdx.x >= o) ? tmp[threadIdx.x - o] : 0;
        __syncthreads();
        tmp[threadIdx.x] += t;
        __syncthreads();
    }
    int incl = tmp[threadIdx.x];
    if (threadIdx.x == 255) base_s = atomicAdd(counter, incl);
    __syncthreads();
    if (n < NN) cursor[n] = base_s + incl - v;   // exclusive within block + base
}

// Place each edge's src into its destination's CSR segment.
__global__ void k_place(const int* __restrict__ src, const int* __restrict__ dst,
                        int* __restrict__ cursor, int* __restrict__ csr_src) {
    int e = blockIdx.x * blockDim.x + threadIdx.x;
    if (e >= EE) return;
    int pos = atomicAdd(&cursor[dst[e]], 1);
    csr_src[pos] = src[e];
}

// ======================= layer-1 gather + fused MLP =========================
// 16 lanes per node, lane = hidden channel. After k_place, cursor[n] = row_end.
// g2[n] = dinv[n] * ( relu( dinv[n]*(sum_{s->n} g1[s] + g1[n]) + b1 ) @ W2 )
__global__ __launch_bounds__(256) void k_agg1(const int* __restrict__ csr,
                                              const int* __restrict__ cursor,
                                              const int* __restrict__ deg,
                                              const float* __restrict__ g1,
                                              const float* __restrict__ dinv,
                                              const float* __restrict__ b1,
                                              const float* __restrict__ W2,
                                              float* __restrict__ g2) {
    int lane = threadIdx.x & 15;
    int n = (blockIdx.x * 256 + threadIdx.x) >> 4;
    if (n >= NN) return;
    int dg = deg[n];
    int rs = cursor[n] - dg;
    float acc = g1[(size_t)n * HIDC + lane];     // self-loop
    int i = 0;
    for (; i + 4 <= dg; i += 4) {                // 4 loads in flight
        int s0 = csr[rs + i + 0];
        int s1 = csr[rs + i + 1];
        int s2 = csr[rs + i + 2];
        int s3 = csr[rs + i + 3];
        float v0 = g1[(size_t)s0 * HIDC + lane];
        float v1 = g1[(size_t)s1 * HIDC + lane];
        float v2 = g1[(size_t)s2 * HIDC + lane];
        float v3 = g1[(size_t)s3 * HIDC + lane];
        acc += v0 + v1 + v2 + v3;
    }
    for (; i < dg; ++i) acc += g1[(size_t)csr[rs + i] * HIDC + lane];
    float dn = dinv[n];
    float h = fmaxf(fmaf(dn, acc, b1[lane]), 0.f);
    float p0 = h * W2[lane * OUTC + 0];
    float p1 = h * W2[lane * OUTC + 1];
#pragma unroll
    for (int o = 8; o; o >>= 1) {
        p0 += __shfl_xor(p0, o, 16);
        p1 += __shfl_xor(p1, o, 16);
    }
    if (lane == 0) {
        float2 v; v.x = dn * p0; v.y = dn * p1;
        ((float2*)g2)[n] = v;
    }
}

// ======================= layer-2 gather + final epilogue ====================
// 8 lanes per node; lane j accumulates edges j, j+8, ... then butterfly.
__global__ __launch_bounds__(256) void k_agg2(const int* __restrict__ csr,
                                              const int* __restrict__ cursor,
                                              const int* __restrict__ deg,
                                              const float* __restrict__ g2,
                                              const float* __restrict__ dinv,
                                              const float* __restrict__ b2,
                                              float* __restrict__ out) {
    int lane = threadIdx.x & 7;
    int n = (blockIdx.x * 256 + threadIdx.x) >> 3;
    if (n >= NN) return;
    int dg = deg[n];
    int rs = cursor[n] - dg;
    float ax = 0.f, ay = 0.f;
    for (int i = lane; i < dg; i += 8) {
        float2 v = ((const float2*)g2)[csr[rs + i]];
        ax += v.x; ay += v.y;
    }
#pragma unroll
    for (int o = 4; o; o >>= 1) {
        ax += __shfl_xor(ax, o, 8);
        ay += __shfl_xor(ay, o, 8);
    }
    if (lane == 0) {
        float dn = dinv[n];
        float2 g = ((const float2*)g2)[n];
        float2 o2;
        o2.x = fmaf(dn, ax + g.x, b2[0]);
        o2.y = fmaf(dn, ay + g.y, b2[1]);
        ((float2*)out)[n] = o2;
    }
}

// ======================= fallback (atomic scatter) kernels ==================

__global__ void k_scatter1(const int* __restrict__ src, const int* __restrict__ dst,
                           const float* __restrict__ g1, float* __restrict__ acc1) {
    int i = blockIdx.x * blockDim.x + threadIdx.x;
    if (i >= EE * 4) return;
    int e = i >> 2, q = i & 3;
    int s = src[e], d = dst[e];
    float4 v = ((const float4*)g1)[s * 4 + q];
    float* p = acc1 + (size_t)d * HIDC + q * 4;
    unsafeAtomicAdd(p + 0, v.x);
    unsafeAtomicAdd(p + 1, v.y);
    unsafeAtomicAdd(p + 2, v.z);
    unsafeAtomicAdd(p + 3, v.w);
}

__global__ void k_l2(const float* __restrict__ g1, const float* __restrict__ acc1,
                     const float* __restrict__ dinv, const float* __restrict__ b1,
                     const float* __restrict__ W2, float* __restrict__ g2) {
    int n = blockIdx.x * blockDim.x + threadIdx.x;
    if (n >= NN) return;
    float dn = dinv[n];
    const float4* a4 = (const float4*)(acc1 + (size_t)n * HIDC);
    const float4* g4 = (const float4*)(g1 + (size_t)n * HIDC);
    float h[HIDC];
#pragma unroll
    for (int q = 0; q < 4; ++q) {
        float4 a = a4[q], g = g4[q];
        h[q * 4 + 0] = fmaxf(dn * (a.x + g.x) + b1[q * 4 + 0], 0.f);
        h[q * 4 + 1] = fmaxf(dn * (a.y + g.y) + b1[q * 4 + 1], 0.f);
        h[q * 4 + 2] = fmaxf(dn * (a.z + g.z) + b1[q * 4 + 2], 0.f);
        h[q * 4 + 3] = fmaxf(dn * (a.w + g.w) + b1[q * 4 + 3], 0.f);
    }
    float o0 = 0.f, o1 = 0.f;
#pragma unroll
    for (int c = 0; c < HIDC; ++c) {
        o0 += h[c] * W2[c * OUTC + 0];
        o1 += h[c] * W2[c * OUTC + 1];
    }
    g2[(size_t)n * OUTC + 0] = dn * o0;
    g2[(size_t)n * OUTC + 1] = dn * o1;
}

__global__ void k_scatter2(const int* __restrict__ src, const int* __restrict__ dst,
                           const float* __restrict__ g2, float* __restrict__ acc2) {
    int e = blockIdx.x * blockDim.x + threadIdx.x;
    if (e >= EE) return;
    int s = src[e], d = dst[e];
    float2 v = ((const float2*)g2)[s];
    unsafeAtomicAdd(&acc2[(size_t)d * OUTC + 0], v.x);
    unsafeAtomicAdd(&acc2[(size_t)d * OUTC + 1], v.y);
}

__global__ void k_final(const float* __restrict__ g2, const float* __restrict__ acc2,
                        const float* __restrict__ dinv, const float* __restrict__ b2,
                        float* __restrict__ out) {
    int n = blockIdx.x * blockDim.x + threadIdx.x;
    if (n >= NN) return;
    float dn = dinv[n];
    float2 a = ((const float2*)acc2)[n];
    float2 g = ((const float2*)g2)[n];
    float2 o;
    o.x = dn * (a.x + g.x) + b2[0];
    o.y = dn * (a.y + g.y) + b2[1];
    ((float2*)out)[n] = o;
}

// ======================= launch =============================================

extern "C" void kernel_launch(void* const* d_in, const int* in_sizes, int n_in,
                              void* d_out, int out_size, void* d_ws, size_t ws_size,
                              hipStream_t stream) {
    const float* x  = (const float*)d_in[0];
    const int*   ei = (const int*)d_in[1];     // [2, E] flat: src then dst
    const float* W1 = (const float*)d_in[2];
    const float* b1 = (const float*)d_in[3];
    const float* W2 = (const float*)d_in[4];
    const float* b2 = (const float*)d_in[5];
    float* out = (float*)d_out;

    const int* src = ei;
    const int* dst = ei + EE;

    const int B = 256;
    int gN  = (NN + B - 1) / B;
    int gE  = (EE + B - 1) / B;

    // CSR-path workspace (elements of 4 B):
    //   deg     [0, N)
    //   counter [N, N+4)
    //   cursor  [N+4, 2N+4)
    //   csr_src [2N+4, 2N+4+E)
    //   dinv    [2N+4+E, 3N+4+E)
    //   g1      [3N+4+E, 19N+4+E)
    //   g2      [19N+4+E, 21N+4+E)
    size_t need = ((size_t)21 * NN + 4 + EE) * 4;
    if (ws_size >= need) {
        int*   ws      = (int*)d_ws;
        int*   deg     = ws;
        int*   counter = ws + NN;
        int*   cursor  = ws + NN + 4;
        int*   csr     = ws + 2 * (size_t)NN + 4;
        float* dinv    = (float*)(ws + 2 * (size_t)NN + 4 + EE);
        float* g1      = (float*)(ws + 3 * (size_t)NN + 4 + EE);
        float* g2      = (float*)(ws + 19 * (size_t)NN + 4 + EE);

        hipMemsetAsync(d_ws, 0, ((size_t)NN + 4) * 4, stream);  // deg + counter

        k_deg  <<<gE, B, 0, stream>>>(dst, deg);
        k_dinv <<<gN, B, 0, stream>>>(deg, dinv);
        k_xw   <<<gN, B, 0, stream>>>(x, W1, dinv, g1);
        k_scan <<<gN, B, 0, stream>>>(deg, cursor, counter);
        k_place<<<gE, B, 0, stream>>>(src, dst, cursor, csr);
        int gA1 = ((NN * 16) + B - 1) / B;
        k_agg1 <<<gA1, B, 0, stream>>>(csr, cursor, deg, g1, dinv, b1, W2, g2);
        int gA2 = ((NN * 8) + B - 1) / B;
        k_agg2 <<<gA2, B, 0, stream>>>(csr, cursor, deg, g2, dinv, b2, out);
        return;
    }

    // -------- fallback: previous atomic-scatter path ------------------------
    char* wsb = (char*)d_ws;
    int*   deg  = (int*)wsb;
    float* acc1 = (float*)(wsb + (size_t)NN * 4);
    float* acc2 = (float*)(wsb + (size_t)17 * NN * 4);
    float* dinv = (float*)(wsb + (size_t)19 * NN * 4);
    float* g1   = (float*)(wsb + (size_t)20 * NN * 4);
    float* g2   = (float*)(wsb + (size_t)36 * NN * 4);

    hipMemsetAsync(d_ws, 0, (size_t)19 * NN * 4, stream);

    int gE4 = (EE * 4 + B - 1) / B;
    k_deg     <<<gE, B, 0, stream>>>(dst, deg);
    k_dinv    <<<gN, B, 0, stream>>>(deg, dinv);
    k_xw      <<<gN, B, 0, stream>>>(x, W1, dinv, g1);
    k_scatter1<<<gE4, B, 0, stream>>>(src, dst, g1, acc1);
    k_l2      <<<gN, B, 0, stream>>>(g1, acc1, dinv, b1, W2, g2);
    k_scatter2<<<gE, B, 0, stream>>>(src, dst, g2, acc2);
    k_final   <<<gN, B, 0, stream>>>(g2, acc2, dinv, b2, out);
}

// Round 3
// 1168.106 us; speedup vs baseline: 1.9936x; 1.0136x over previous
//
#include <hip/hip_runtime.h>

#define NN   200000
#define EE   6400000
#define INC  128
#define HIDC 16
#define OUTC 2

#define TN     256                 // nodes per tile
#define TSHIFT 8
#define TMASK  (TN - 1)
#define NT     782                 // ceil(NN / TN)
#define CHUNK  8192                // edges per hist/place block
#define NBE    782                 // ceil(EE / CHUNK)

// ---------------- coarse histogram over dst tiles ---------------------------
__global__ __launch_bounds__(256) void k_hist(const int* __restrict__ dst,
                                              int* __restrict__ tile_counts) {
    __shared__ int h[NT];
    for (int t = threadIdx.x; t < NT; t += 256) h[t] = 0;
    __syncthreads();
    int base = blockIdx.x * CHUNK;
    for (int i = threadIdx.x; i < CHUNK; i += 256) {
        int e = base + i;
        if (e < EE) atomicAdd(&h[dst[e] >> TSHIFT], 1);
    }
    __syncthreads();
    for (int t = threadIdx.x; t < NT; t += 256)
        if (h[t]) atomicAdd(&tile_counts[t], h[t]);
}

// ---------------- exclusive scan of tile counts (single block) --------------
__global__ __launch_bounds__(1024) void k_scan(const int* __restrict__ tile_counts,
                                               int* __restrict__ tile_base,
                                               int* __restrict__ tile_cursor) {
    __shared__ int tmp[1024];
    int t = threadIdx.x;
    int v = (t < NT) ? tile_counts[t] : 0;
    tmp[t] = v;
    __syncthreads();
    for (int o = 1; o < 1024; o <<= 1) {
        int u = (t >= o) ? tmp[t - o] : 0;
        __syncthreads();
        tmp[t] += u;
        __syncthreads();
    }
    if (t < NT) {
        int ex = tmp[t] - v;
        tile_base[t] = ex;
        tile_cursor[t] = ex;
    }
}

// ---------------- place edges into tile buckets -----------------------------
// record = (src << 8) | (dst & 255); tile implied by position.
__global__ __launch_bounds__(256) void k_bplace(const int* __restrict__ src,
                                                const int* __restrict__ dst,
                                                int* __restrict__ tile_cursor,
                                                int* __restrict__ brec) {
    __shared__ int h[NT];
    __shared__ int lcur[NT];
    for (int t = threadIdx.x; t < NT; t += 256) h[t] = 0;
    __syncthreads();
    int base = blockIdx.x * CHUNK;
    for (int i = threadIdx.x; i < CHUNK; i += 256) {
        int e = base + i;
        if (e < EE) atomicAdd(&h[dst[e] >> TSHIFT], 1);
    }
    __syncthreads();
    for (int t = threadIdx.x; t < NT; t += 256) {
        int c = h[t];
        lcur[t] = c ? atomicAdd(&tile_cursor[t], c) : 0;
    }
    __syncthreads();
    for (int i = threadIdx.x; i < CHUNK; i += 256) {
        int e = base + i;
        if (e < EE) {
            int d = dst[e];
            int pos = atomicAdd(&lcur[d >> TSHIFT], 1);
            brec[pos] = (src[e] << 8) | (d & TMASK);
        }
    }
}

// ---------------- per-tile degree -> dinv -----------------------------------
__global__ __launch_bounds__(256) void k_tdeg(const int* __restrict__ brec,
                                              const int* __restrict__ tile_base,
                                              const int* __restrict__ tile_counts,
                                              float* __restrict__ dinv) {
    __shared__ int degs[TN];
    int t = blockIdx.x;
    degs[threadIdx.x] = 0;
    __syncthreads();
    int s0 = tile_base[t], cnt = tile_counts[t];
    for (int i = threadIdx.x; i < cnt; i += 256)
        atomicAdd(&degs[brec[s0 + i] & TMASK], 1);
    __syncthreads();
    int node = t * TN + threadIdx.x;
    if (node < NN) dinv[node] = rsqrtf((float)(degs[threadIdx.x] + 1)); // +1 self-loop
}

// ---------------- g1 = dinv * (x @ W1) --------------------------------------
__global__ __launch_bounds__(256) void k_xw(const float* __restrict__ x,
                                            const float* __restrict__ W1,
                                            const float* __restrict__ dinv,
                                            float* __restrict__ g1) {
    __shared__ float Ws[INC * HIDC];           // 8 KB
    for (int j = threadIdx.x; j < INC * HIDC; j += 256) Ws[j] = W1[j];
    __syncthreads();
    int n = blockIdx.x * 256 + threadIdx.x;
    if (n >= NN) return;
    const float4* xr = (const float4*)(x + (size_t)n * INC);
    float acc[HIDC];
#pragma unroll
    for (int c = 0; c < HIDC; ++c) acc[c] = 0.f;
    for (int k4 = 0; k4 < INC / 4; ++k4) {
        float4 xv = xr[k4];
        const float* w0 = &Ws[(k4 * 4) * HIDC];
        float xs[4] = {xv.x, xv.y, xv.z, xv.w};
#pragma unroll
        for (int j = 0; j < 4; ++j) {
#pragma unroll
            for (int c = 0; c < HIDC; ++c) acc[c] += xs[j] * w0[j * HIDC + c];
        }
    }
    float dn = dinv[n];
    float4* gout = (float4*)(g1 + (size_t)n * HIDC);
#pragma unroll
    for (int q = 0; q < 4; ++q) {
        float4 v;
        v.x = dn * acc[q * 4 + 0];
        v.y = dn * acc[q * 4 + 1];
        v.z = dn * acc[q * 4 + 2];
        v.w = dn * acc[q * 4 + 3];
        gout[q] = v;
    }
}

// ---------------- layer-1 per-tile aggregate + fused MLP --------------------
// g2[n] = dinv[n] * ( relu( dinv[n]*(sum g1[s] + g1[n]) + b1 ) @ W2 )
__global__ __launch_bounds__(256) void k_agg1t(const int* __restrict__ brec,
                                               const int* __restrict__ tile_base,
                                               const int* __restrict__ tile_counts,
                                               const float* __restrict__ g1,
                                               const float* __restrict__ dinv,
                                               const float* __restrict__ b1,
                                               const float* __restrict__ W2,
                                               float* __restrict__ g2) {
    __shared__ float acc[TN * HIDC];           // 16 KB
    int t = blockIdx.x;
    for (int i = threadIdx.x; i < TN * HIDC; i += 256) acc[i] = 0.f;
    __syncthreads();
    int s0 = tile_base[t], cnt = tile_counts[t];
    int q = threadIdx.x & 3;                   // float4 quarter of the row
    for (int i = threadIdx.x >> 2; i < cnt; i += 64) {
        int rec = brec[s0 + i];
        int s = rec >> 8, dl = rec & TMASK;
        float4 v = ((const float4*)g1)[s * 4 + q];
        float* a = &acc[dl * HIDC + q * 4];
        unsafeAtomicAdd(a + 0, v.x);
        unsafeAtomicAdd(a + 1, v.y);
        unsafeAtomicAdd(a + 2, v.z);
        unsafeAtomicAdd(a + 3, v.w);
    }
    __syncthreads();
    int lane = threadIdx.x & 15;
    int nb = t * TN;
    for (int nn = threadIdx.x >> 4; nn < TN; nn += 16) {
        int node = nb + nn;
        if (node < NN) {                       // uniform across the 16-lane group
            float a = acc[nn * HIDC + lane];
            float self = g1[(size_t)node * HIDC + lane];
            float dn = dinv[node];
            float h = fmaxf(fmaf(dn, a + self, b1[lane]), 0.f);
            float p0 = h * W2[lane * OUTC + 0];
            float p1 = h * W2[lane * OUTC + 1];
#pragma unroll
            for (int o = 8; o; o >>= 1) {
                p0 += __shfl_xor(p0, o, 16);
                p1 += __shfl_xor(p1, o, 16);
            }
            if (lane == 0) {
                float2 v; v.x = dn * p0; v.y = dn * p1;
                ((float2*)g2)[node] = v;
            }
        }
    }
}

// ---------------- layer-2 per-tile aggregate + final epilogue ---------------
__global__ __launch_bounds__(256) void k_agg2t(const int* __restrict__ brec,
                                               const int* __restrict__ tile_base,
                                               const int* __restrict__ tile_counts,
                                               const float* __restrict__ g2,
                                               const float* __restrict__ dinv,
                                               const float* __restrict__ b2,
                                               float* __restrict__ out) {
    __shared__ float acc[TN * OUTC];           // 2 KB
    int t = blockIdx.x;
    for (int i = threadIdx.x; i < TN * OUTC; i += 256) acc[i] = 0.f;
    __syncthreads();
    int s0 = tile_base[t], cnt = tile_counts[t];
    for (int i = threadIdx.x; i < cnt; i += 256) {
        int rec = brec[s0 + i];
        int s = rec >> 8, dl = rec & TMASK;
        float2 v = ((const float2*)g2)[s];
        unsafeAtomicAdd(&acc[dl * OUTC + 0], v.x);
        unsafeAtomicAdd(&acc[dl * OUTC + 1], v.y);
    }
    __syncthreads();
    int node = t * TN + threadIdx.x;
    if (node < NN) {
        float dn = dinv[node];
        float2 g = ((const float2*)g2)[node];
        float2 o;
        o.x = fmaf(dn, acc[threadIdx.x * OUTC + 0] + g.x, b2[0]);
        o.y = fmaf(dn, acc[threadIdx.x * OUTC + 1] + g.y, b2[1]);
        ((float2*)out)[node] = o;
    }
}

// ======================= fallback (atomic scatter) kernels ==================

__global__ void k_deg_f(const int* __restrict__ dst, int* __restrict__ deg) {
    int i = blockIdx.x * blockDim.x + threadIdx.x;
    if (i < EE) atomicAdd(&deg[dst[i]], 1);
}
__global__ void k_dinv_f(const int* __restrict__ deg, float* __restrict__ dinv) {
    int n = blockIdx.x * blockDim.x + threadIdx.x;
    if (n < NN) dinv[n] = rsqrtf((float)(deg[n] + 1));
}
__global__ void k_scatter1_f(const int* __restrict__ src, const int* __restrict__ dst,
                             const float* __restrict__ g1, float* __restrict__ acc1) {
    int i = blockIdx.x * blockDim.x + threadIdx.x;
    if (i >= EE * 4) return;
    int e = i >> 2, q = i & 3;
    float4 v = ((const float4*)g1)[src[e] * 4 + q];
    float* p = acc1 + (size_t)dst[e] * HIDC + q * 4;
    unsafeAtomicAdd(p + 0, v.x); unsafeAtomicAdd(p + 1, v.y);
    unsafeAtomicAdd(p + 2, v.z); unsafeAtomicAdd(p + 3, v.w);
}
__global__ void k_l2_f(const float* __restrict__ g1, const float* __restrict__ acc1,
                       const float* __restrict__ dinv, const float* __restrict__ b1,
                       const float* __restrict__ W2, float* __restrict__ g2) {
    int n = blockIdx.x * blockDim.x + threadIdx.x;
    if (n >= NN) return;
    float dn = dinv[n];
    float h[HIDC];
#pragma unroll
    for (int c = 0; c < HIDC; ++c)
        h[c] = fmaxf(dn * (acc1[(size_t)n * HIDC + c] + g1[(size_t)n * HIDC + c]) + b1[c], 0.f);
    float o0 = 0.f, o1 = 0.f;
#pragma unroll
    for (int c = 0; c < HIDC; ++c) { o0 += h[c] * W2[c * 2]; o1 += h[c] * W2[c * 2 + 1]; }
    g2[(size_t)n * 2] = dn * o0; g2[(size_t)n * 2 + 1] = dn * o1;
}
__global__ void k_scatter2_f(const int* __restrict__ src, const int* __restrict__ dst,
                             const float* __restrict__ g2, float* __restrict__ acc2) {
    int e = blockIdx.x * blockDim.x + threadIdx.x;
    if (e >= EE) return;
    float2 v = ((const float2*)g2)[src[e]];
    unsafeAtomicAdd(&acc2[(size_t)dst[e] * 2], v.x);
    unsafeAtomicAdd(&acc2[(size_t)dst[e] * 2 + 1], v.y);
}
__global__ void k_final_f(const float* __restrict__ g2, const float* __restrict__ acc2,
                          const float* __restrict__ dinv, const float* __restrict__ b2,
                          float* __restrict__ out) {
    int n = blockIdx.x * blockDim.x + threadIdx.x;
    if (n >= NN) return;
    float dn = dinv[n];
    float2 a = ((const float2*)acc2)[n];
    float2 g = ((const float2*)g2)[n];
    float2 o;
    o.x = dn * (a.x + g.x) + b2[0];
    o.y = dn * (a.y + g.y) + b2[1];
    ((float2*)out)[n] = o;
}

// ======================= launch =============================================

extern "C" void kernel_launch(void* const* d_in, const int* in_sizes, int n_in,
                              void* d_out, int out_size, void* d_ws, size_t ws_size,
                              hipStream_t stream) {
    const float* x  = (const float*)d_in[0];
    const int*   ei = (const int*)d_in[1];     // [2, E] flat: src then dst
    const float* W1 = (const float*)d_in[2];
    const float* b1 = (const float*)d_in[3];
    const float* W2 = (const float*)d_in[4];
    const float* b2 = (const float*)d_in[5];
    float* out = (float*)d_out;

    const int* src = ei;
    const int* dst = ei + EE;
    const int B = 256;

    // tile-path workspace (4 B elements):
    //   tile_counts [0, NT)
    //   tile_base   [NT, 2NT)
    //   tile_cursor [2NT, 3NT)
    //   brec        [3NT, 3NT+E)
    //   dinv        [.., +N)
    //   g1          [.., +16N)
    //   g2          [.., +2N)
    size_t need = ((size_t)3 * NT + EE + (size_t)19 * NN) * 4;   // ~40.8 MB
    if (ws_size >= need) {
        int* ws          = (int*)d_ws;
        int* tile_counts = ws;
        int* tile_base   = ws + NT;
        int* tile_cursor = ws + 2 * NT;
        int* brec        = ws + 3 * NT;
        float* dinv      = (float*)(ws + 3 * NT + EE);
        float* g1        = dinv + NN;
        float* g2        = g1 + (size_t)NN * HIDC;

        hipMemsetAsync(tile_counts, 0, (size_t)NT * 4, stream);

        k_hist  <<<NBE, B, 0, stream>>>(dst, tile_counts);
        k_scan  <<<1, 1024, 0, stream>>>(tile_counts, tile_base, tile_cursor);
        k_bplace<<<NBE, B, 0, stream>>>(src, dst, tile_cursor, brec);
        k_tdeg  <<<NT, B, 0, stream>>>(brec, tile_base, tile_counts, dinv);
        k_xw    <<<(NN + B - 1) / B, B, 0, stream>>>(x, W1, dinv, g1);
        k_agg1t <<<NT, B, 0, stream>>>(brec, tile_base, tile_counts, g1, dinv, b1, W2, g2);
        k_agg2t <<<NT, B, 0, stream>>>(brec, tile_base, tile_counts, g2, dinv, b2, out);
        return;
    }

    // -------- fallback: atomic-scatter path (needs 38N floats) --------------
    char* wsb = (char*)d_ws;
    int*   deg  = (int*)wsb;
    float* acc1 = (float*)(wsb + (size_t)NN * 4);
    float* acc2 = (float*)(wsb + (size_t)17 * NN * 4);
    float* dinv = (float*)(wsb + (size_t)19 * NN * 4);
    float* g1   = (float*)(wsb + (size_t)20 * NN * 4);
    float* g2   = (float*)(wsb + (size_t)36 * NN * 4);

    hipMemsetAsync(d_ws, 0, (size_t)19 * NN * 4, stream);

    int gN = (NN + B - 1) / B, gE = (EE + B - 1) / B, gE4 = (EE * 4 + B - 1) / B;
    k_deg_f     <<<gE, B, 0, stream>>>(dst, deg);
    k_dinv_f    <<<gN, B, 0, stream>>>(deg, dinv);
    k_xw        <<<gN, B, 0, stream>>>(x, W1, dinv, g1);
    k_scatter1_f<<<gE4, B, 0, stream>>>(src, dst, g1, acc1);
    k_l2_f      <<<gN, B, 0, stream>>>(g1, acc1, dinv, b1, W2, g2);
    k_scatter2_f<<<gE, B, 0, stream>>>(src, dst, g2, acc2);
    k_final_f   <<<gN, B, 0, stream>>>(g2, acc2, dinv, b2, out);
}

// Round 4
// 1137.383 us; speedup vs baseline: 2.0475x; 1.0270x over previous
//
#include <hip/hip_runtime.h>

#define NN   200000
#define EE   6400000
#define INC  128
#define HIDC 16
#define OUTC 2

#define TN     256                 // nodes per tile
#define TSHIFT 8
#define TMASK  (TN - 1)
#define NT     782                 // ceil(NN / TN)
#define CHUNK  8192                // edges per hist/place block
#define NBE    782                 // ceil(EE / CHUNK)
#define SP1    17                  // padded LDS stride, layer-1 acc
#define SP2    3                   // padded LDS stride, layer-2 acc

// ---------------- coarse histogram over dst tiles ---------------------------
__global__ __launch_bounds__(256) void k_hist(const int* __restrict__ dst,
                                              int* __restrict__ tile_counts) {
    __shared__ int h[NT];
    for (int t = threadIdx.x; t < NT; t += 256) h[t] = 0;
    __syncthreads();
    int base = blockIdx.x * CHUNK;
    if (base + CHUNK <= EE) {
        for (int i = threadIdx.x; i < CHUNK; i += 1024) {
            int d0 = dst[base + i];
            int d1 = dst[base + i + 256];
            int d2 = dst[base + i + 512];
            int d3 = dst[base + i + 768];
            atomicAdd(&h[d0 >> TSHIFT], 1);
            atomicAdd(&h[d1 >> TSHIFT], 1);
            atomicAdd(&h[d2 >> TSHIFT], 1);
            atomicAdd(&h[d3 >> TSHIFT], 1);
        }
    } else {
        for (int i = threadIdx.x; i < CHUNK; i += 256) {
            int e = base + i;
            if (e < EE) atomicAdd(&h[dst[e] >> TSHIFT], 1);
        }
    }
    __syncthreads();
    for (int t = threadIdx.x; t < NT; t += 256)
        if (h[t]) atomicAdd(&tile_counts[t], h[t]);
}

// ---------------- exclusive scan of tile counts (single block) --------------
__global__ __launch_bounds__(1024) void k_scan(const int* __restrict__ tile_counts,
                                               int* __restrict__ tile_base,
                                               int* __restrict__ tile_cursor) {
    __shared__ int tmp[1024];
    int t = threadIdx.x;
    int v = (t < NT) ? tile_counts[t] : 0;
    tmp[t] = v;
    __syncthreads();
    for (int o = 1; o < 1024; o <<= 1) {
        int u = (t >= o) ? tmp[t - o] : 0;
        __syncthreads();
        tmp[t] += u;
        __syncthreads();
    }
    if (t < NT) {
        int ex = tmp[t] - v;
        tile_base[t] = ex;
        tile_cursor[t] = ex;
    }
}

// ---------------- place edges into tile buckets -----------------------------
// record = (src << 8) | (dst & 255); tile implied by position.
__global__ __launch_bounds__(256) void k_bplace(const int* __restrict__ src,
                                                const int* __restrict__ dst,
                                                int* __restrict__ tile_cursor,
                                                int* __restrict__ brec) {
    __shared__ int h[NT];
    __shared__ int lcur[NT];
    for (int t = threadIdx.x; t < NT; t += 256) h[t] = 0;
    __syncthreads();
    int base = blockIdx.x * CHUNK;
    bool full = (base + CHUNK <= EE);
    if (full) {
        for (int i = threadIdx.x; i < CHUNK; i += 1024) {
            int d0 = dst[base + i];
            int d1 = dst[base + i + 256];
            int d2 = dst[base + i + 512];
            int d3 = dst[base + i + 768];
            atomicAdd(&h[d0 >> TSHIFT], 1);
            atomicAdd(&h[d1 >> TSHIFT], 1);
            atomicAdd(&h[d2 >> TSHIFT], 1);
            atomicAdd(&h[d3 >> TSHIFT], 1);
        }
    } else {
        for (int i = threadIdx.x; i < CHUNK; i += 256) {
            int e = base + i;
            if (e < EE) atomicAdd(&h[dst[e] >> TSHIFT], 1);
        }
    }
    __syncthreads();
    for (int t = threadIdx.x; t < NT; t += 256) {
        int c = h[t];
        lcur[t] = c ? atomicAdd(&tile_cursor[t], c) : 0;
    }
    __syncthreads();
    if (full) {
        for (int i = threadIdx.x; i < CHUNK; i += 1024) {
            int e = base + i;
            int d0 = dst[e], d1 = dst[e + 256], d2 = dst[e + 512], d3 = dst[e + 768];
            int s0 = src[e], s1 = src[e + 256], s2 = src[e + 512], s3 = src[e + 768];
            int p0 = atomicAdd(&lcur[d0 >> TSHIFT], 1);
            int p1 = atomicAdd(&lcur[d1 >> TSHIFT], 1);
            int p2 = atomicAdd(&lcur[d2 >> TSHIFT], 1);
            int p3 = atomicAdd(&lcur[d3 >> TSHIFT], 1);
            brec[p0] = (s0 << 8) | (d0 & TMASK);
            brec[p1] = (s1 << 8) | (d1 & TMASK);
            brec[p2] = (s2 << 8) | (d2 & TMASK);
            brec[p3] = (s3 << 8) | (d3 & TMASK);
        }
    } else {
        for (int i = threadIdx.x; i < CHUNK; i += 256) {
            int e = base + i;
            if (e < EE) {
                int d = dst[e];
                int pos = atomicAdd(&lcur[d >> TSHIFT], 1);
                brec[pos] = (src[e] << 8) | (d & TMASK);
            }
        }
    }
}

// ---------------- per-tile degree -> dinv -----------------------------------
__global__ __launch_bounds__(512) void k_tdeg(const int* __restrict__ brec,
                                              const int* __restrict__ tile_base,
                                              const int* __restrict__ tile_counts,
                                              float* __restrict__ dinv) {
    __shared__ int degs[TN];
    int t = blockIdx.x;
    if (threadIdx.x < TN) degs[threadIdx.x] = 0;
    __syncthreads();
    int s0 = tile_base[t], cnt = tile_counts[t];
    int i = threadIdx.x;
    for (; i + 1536 < cnt; i += 2048) {
        int r0 = brec[s0 + i];
        int r1 = brec[s0 + i + 512];
        int r2 = brec[s0 + i + 1024];
        int r3 = brec[s0 + i + 1536];
        atomicAdd(&degs[r0 & TMASK], 1);
        atomicAdd(&degs[r1 & TMASK], 1);
        atomicAdd(&degs[r2 & TMASK], 1);
        atomicAdd(&degs[r3 & TMASK], 1);
    }
    for (; i < cnt; i += 512) atomicAdd(&degs[brec[s0 + i] & TMASK], 1);
    __syncthreads();
    int node = t * TN + threadIdx.x;
    if (threadIdx.x < TN && node < NN)
        dinv[node] = rsqrtf((float)(degs[threadIdx.x] + 1));   // +1 = self-loop
}

// ---------------- g1 = dinv * (x @ W1) --------------------------------------
__global__ __launch_bounds__(256) void k_xw(const float* __restrict__ x,
                                            const float* __restrict__ W1,
                                            const float* __restrict__ dinv,
                                            float* __restrict__ g1) {
    __shared__ float Ws[INC * HIDC];           // 8 KB
    for (int j = threadIdx.x; j < INC * HIDC; j += 256) Ws[j] = W1[j];
    __syncthreads();
    int n = blockIdx.x * 256 + threadIdx.x;
    if (n >= NN) return;
    const float4* xr = (const float4*)(x + (size_t)n * INC);
    float acc[HIDC];
#pragma unroll
    for (int c = 0; c < HIDC; ++c) acc[c] = 0.f;
    for (int k4 = 0; k4 < INC / 4; ++k4) {
        float4 xv = xr[k4];
        const float* w0 = &Ws[(k4 * 4) * HIDC];
        float xs[4] = {xv.x, xv.y, xv.z, xv.w};
#pragma unroll
        for (int j = 0; j < 4; ++j) {
#pragma unroll
            for (int c = 0; c < HIDC; ++c) acc[c] += xs[j] * w0[j * HIDC + c];
        }
    }
    float dn = dinv[n];
    float4* gout = (float4*)(g1 + (size_t)n * HIDC);
#pragma unroll
    for (int q = 0; q < 4; ++q) {
        float4 v;
        v.x = dn * acc[q * 4 + 0];
        v.y = dn * acc[q * 4 + 1];
        v.z = dn * acc[q * 4 + 2];
        v.w = dn * acc[q * 4 + 3];
        gout[q] = v;
    }
}

// ---------------- layer-1 per-tile aggregate + fused MLP --------------------
// One lane per edge: 4 independent float4 loads (64 B, one line), 16 LDS
// fp32 atomics into a stride-17-padded accumulator (banks spread by 17*dl).
// g2[n] = dinv[n] * ( relu( dinv[n]*(sum g1[s] + g1[n]) + b1 ) @ W2 )
__global__ __launch_bounds__(512) void k_agg1t(const int* __restrict__ brec,
                                               const int* __restrict__ tile_base,
                                               const int* __restrict__ tile_counts,
                                               const float* __restrict__ g1,
                                               const float* __restrict__ dinv,
                                               const float* __restrict__ b1,
                                               const float* __restrict__ W2,
                                               float* __restrict__ g2) {
    __shared__ float acc[TN * SP1];            // 17 KB
    int t = blockIdx.x;
    for (int i = threadIdx.x; i < TN * SP1; i += 512) acc[i] = 0.f;
    __syncthreads();
    int s0 = tile_base[t], cnt = tile_counts[t];
    int i = threadIdx.x;
    for (; i + 512 < cnt; i += 1024) {         // unroll x2: 8 gathers in flight
        int r0 = brec[s0 + i];
        int r1 = brec[s0 + i + 512];
        const float4* p0 = (const float4*)g1 + (size_t)(r0 >> 8) * 4;
        const float4* p1 = (const float4*)g1 + (size_t)(r1 >> 8) * 4;
        float4 a0 = p0[0], a1 = p0[1], a2 = p0[2], a3 = p0[3];
        float4 c0 = p1[0], c1 = p1[1], c2 = p1[2], c3 = p1[3];
        float* d0 = &acc[(r0 & TMASK) * SP1];
        float* d1 = &acc[(r1 & TMASK) * SP1];
        atomicAdd(d0 + 0,  a0.x); atomicAdd(d0 + 1,  a0.y);
        atomicAdd(d0 + 2,  a0.z); atomicAdd(d0 + 3,  a0.w);
        atomicAdd(d0 + 4,  a1.x); atomicAdd(d0 + 5,  a1.y);
        atomicAdd(d0 + 6,  a1.z); atomicAdd(d0 + 7,  a1.w);
        atomicAdd(d0 + 8,  a2.x); atomicAdd(d0 + 9,  a2.y);
        atomicAdd(d0 + 10, a2.z); atomicAdd(d0 + 11, a2.w);
        atomicAdd(d0 + 12, a3.x); atomicAdd(d0 + 13, a3.y);
        atomicAdd(d0 + 14, a3.z); atomicAdd(d0 + 15, a3.w);
        atomicAdd(d1 + 0,  c0.x); atomicAdd(d1 + 1,  c0.y);
        atomicAdd(d1 + 2,  c0.z); atomicAdd(d1 + 3,  c0.w);
        atomicAdd(d1 + 4,  c1.x); atomicAdd(d1 + 5,  c1.y);
        atomicAdd(d1 + 6,  c1.z); atomicAdd(d1 + 7,  c1.w);
        atomicAdd(d1 + 8,  c2.x); atomicAdd(d1 + 9,  c2.y);
        atomicAdd(d1 + 10, c2.z); atomicAdd(d1 + 11, c2.w);
        atomicAdd(d1 + 12, c3.x); atomicAdd(d1 + 13, c3.y);
        atomicAdd(d1 + 14, c3.z); atomicAdd(d1 + 15, c3.w);
    }
    for (; i < cnt; i += 512) {
        int r0 = brec[s0 + i];
        const float4* p0 = (const float4*)g1 + (size_t)(r0 >> 8) * 4;
        float4 a0 = p0[0], a1 = p0[1], a2 = p0[2], a3 = p0[3];
        float* d0 = &acc[(r0 & TMASK) * SP1];
        atomicAdd(d0 + 0,  a0.x); atomicAdd(d0 + 1,  a0.y);
        atomicAdd(d0 + 2,  a0.z); atomicAdd(d0 + 3,  a0.w);
        atomicAdd(d0 + 4,  a1.x); atomicAdd(d0 + 5,  a1.y);
        atomicAdd(d0 + 6,  a1.z); atomicAdd(d0 + 7,  a1.w);
        atomicAdd(d0 + 8,  a2.x); atomicAdd(d0 + 9,  a2.y);
        atomicAdd(d0 + 10, a2.z); atomicAdd(d0 + 11, a2.w);
        atomicAdd(d0 + 12, a3.x); atomicAdd(d0 + 13, a3.y);
        atomicAdd(d0 + 14, a3.z); atomicAdd(d0 + 15, a3.w);
    }
    __syncthreads();
    int lane = threadIdx.x & 15;
    int nb = t * TN;
    for (int nn = threadIdx.x >> 4; nn < TN; nn += 32) {
        int node = nb + nn;
        if (node < NN) {                       // uniform across the 16-lane group
            float a = acc[nn * SP1 + lane];
            float self = g1[(size_t)node * HIDC + lane];
            float dn = dinv[node];
            float h = fmaxf(fmaf(dn, a + self, b1[lane]), 0.f);
            float p0 = h * W2[lane * OUTC + 0];
            float p1 = h * W2[lane * OUTC + 1];
#pragma unroll
            for (int o = 8; o; o >>= 1) {
                p0 += __shfl_xor(p0, o, 16);
                p1 += __shfl_xor(p1, o, 16);
            }
            if (lane == 0) {
                float2 v; v.x = dn * p0; v.y = dn * p1;
                ((float2*)g2)[node] = v;
            }
        }
    }
}

// ---------------- layer-2 per-tile aggregate + final epilogue ---------------
__global__ __launch_bounds__(512) void k_agg2t(const int* __restrict__ brec,
                                               const int* __restrict__ tile_base,
                                               const int* __restrict__ tile_counts,
                                               const float* __restrict__ g2,
                                               const float* __restrict__ dinv,
                                               const float* __restrict__ b2,
                                               float* __restrict__ out) {
    __shared__ float acc[TN * SP2];            // 3 KB, stride-3 padded
    int t = blockIdx.x;
    for (int i = threadIdx.x; i < TN * SP2; i += 512) acc[i] = 0.f;
    __syncthreads();
    int s0 = tile_base[t], cnt = tile_counts[t];
    int i = threadIdx.x;
    for (; i + 1536 < cnt; i += 2048) {        // unroll x4
        int r0 = brec[s0 + i];
        int r1 = brec[s0 + i + 512];
        int r2 = brec[s0 + i + 1024];
        int r3 = brec[s0 + i + 1536];
        float2 v0 = ((const float2*)g2)[r0 >> 8];
        float2 v1 = ((const float2*)g2)[r1 >> 8];
        float2 v2 = ((const float2*)g2)[r2 >> 8];
        float2 v3 = ((const float2*)g2)[r3 >> 8];
        atomicAdd(&acc[(r0 & TMASK) * SP2 + 0], v0.x);
        atomicAdd(&acc[(r0 & TMASK) * SP2 + 1], v0.y);
        atomicAdd(&acc[(r1 & TMASK) * SP2 + 0], v1.x);
        atomicAdd(&acc[(r1 & TMASK) * SP2 + 1], v1.y);
        atomicAdd(&acc[(r2 & TMASK) * SP2 + 0], v2.x);
        atomicAdd(&acc[(r2 & TMASK) * SP2 + 1], v2.y);
        atomicAdd(&acc[(r3 & TMASK) * SP2 + 0], v3.x);
        atomicAdd(&acc[(r3 & TMASK) * SP2 + 1], v3.y);
    }
    for (; i < cnt; i += 512) {
        int r0 = brec[s0 + i];
        float2 v0 = ((const float2*)g2)[r0 >> 8];
        atomicAdd(&acc[(r0 & TMASK) * SP2 + 0], v0.x);
        atomicAdd(&acc[(r0 & TMASK) * SP2 + 1], v0.y);
    }
    __syncthreads();
    int node = t * TN + threadIdx.x;
    if (threadIdx.x < TN && node < NN) {
        float dn = dinv[node];
        float2 g = ((const float2*)g2)[node];
        float2 o;
        o.x = fmaf(dn, acc[threadIdx.x * SP2 + 0] + g.x, b2[0]);
        o.y = fmaf(dn, acc[threadIdx.x * SP2 + 1] + g.y, b2[1]);
        ((float2*)out)[node] = o;
    }
}

// ======================= fallback (atomic scatter) kernels ==================

__global__ void k_deg_f(const int* __restrict__ dst, int* __restrict__ deg) {
    int i = blockIdx.x * blockDim.x + threadIdx.x;
    if (i < EE) atomicAdd(&deg[dst[i]], 1);
}
__global__ void k_dinv_f(const int* __restrict__ deg, float* __restrict__ dinv) {
    int n = blockIdx.x * blockDim.x + threadIdx.x;
    if (n < NN) dinv[n] = rsqrtf((float)(deg[n] + 1));
}
__global__ void k_scatter1_f(const int* __restrict__ src, const int* __restrict__ dst,
                             const float* __restrict__ g1, float* __restrict__ acc1) {
    int i = blockIdx.x * blockDim.x + threadIdx.x;
    if (i >= EE * 4) return;
    int e = i >> 2, q = i & 3;
    float4 v = ((const float4*)g1)[src[e] * 4 + q];
    float* p = acc1 + (size_t)dst[e] * HIDC + q * 4;
    unsafeAtomicAdd(p + 0, v.x); unsafeAtomicAdd(p + 1, v.y);
    unsafeAtomicAdd(p + 2, v.z); unsafeAtomicAdd(p + 3, v.w);
}
__global__ void k_l2_f(const float* __restrict__ g1, const float* __restrict__ acc1,
                       const float* __restrict__ dinv, const float* __restrict__ b1,
                       const float* __restrict__ W2, float* __restrict__ g2) {
    int n = blockIdx.x * blockDim.x + threadIdx.x;
    if (n >= NN) return;
    float dn = dinv[n];
    float h[HIDC];
#pragma unroll
    for (int c = 0; c < HIDC; ++c)
        h[c] = fmaxf(dn * (acc1[(size_t)n * HIDC + c] + g1[(size_t)n * HIDC + c]) + b1[c], 0.f);
    float o0 = 0.f, o1 = 0.f;
#pragma unroll
    for (int c = 0; c < HIDC; ++c) { o0 += h[c] * W2[c * 2]; o1 += h[c] * W2[c * 2 + 1]; }
    g2[(size_t)n * 2] = dn * o0; g2[(size_t)n * 2 + 1] = dn * o1;
}
__global__ void k_scatter2_f(const int* __restrict__ src, const int* __restrict__ dst,
                             const float* __restrict__ g2, float* __restrict__ acc2) {
    int e = blockIdx.x * blockDim.x + threadIdx.x;
    if (e >= EE) return;
    float2 v = ((const float2*)g2)[src[e]];
    unsafeAtomicAdd(&acc2[(size_t)dst[e] * 2], v.x);
    unsafeAtomicAdd(&acc2[(size_t)dst[e] * 2 + 1], v.y);
}
__global__ void k_final_f(const float* __restrict__ g2, const float* __restrict__ acc2,
                          const float* __restrict__ dinv, const float* __restrict__ b2,
                          float* __restrict__ out) {
    int n = blockIdx.x * blockDim.x + threadIdx.x;
    if (n >= NN) return;
    float dn = dinv[n];
    float2 a = ((const float2*)acc2)[n];
    float2 g = ((const float2*)g2)[n];
    float2 o;
    o.x = dn * (a.x + g.x) + b2[0];
    o.y = dn * (a.y + g.y) + b2[1];
    ((float2*)out)[n] = o;
}

// ======================= launch =============================================

extern "C" void kernel_launch(void* const* d_in, const int* in_sizes, int n_in,
                              void* d_out, int out_size, void* d_ws, size_t ws_size,
                              hipStream_t stream) {
    const float* x  = (const float*)d_in[0];
    const int*   ei = (const int*)d_in[1];     // [2, E] flat: src then dst
    const float* W1 = (const float*)d_in[2];
    const float* b1 = (const float*)d_in[3];
    const float* W2 = (const float*)d_in[4];
    const float* b2 = (const float*)d_in[5];
    float* out = (float*)d_out;

    const int* src = ei;
    const int* dst = ei + EE;
    const int B = 256;

    size_t need = ((size_t)3 * NT + EE + (size_t)19 * NN) * 4;   // ~40.8 MB
    if (ws_size >= need) {
        int* ws          = (int*)d_ws;
        int* tile_counts = ws;
        int* tile_base   = ws + NT;
        int* tile_cursor = ws + 2 * NT;
        int* brec        = ws + 3 * NT;
        float* dinv      = (float*)(ws + 3 * NT + EE);
        float* g1        = dinv + NN;
        float* g2        = g1 + (size_t)NN * HIDC;

        hipMemsetAsync(tile_counts, 0, (size_t)NT * 4, stream);

        k_hist  <<<NBE, B, 0, stream>>>(dst, tile_counts);
        k_scan  <<<1, 1024, 0, stream>>>(tile_counts, tile_base, tile_cursor);
        k_bplace<<<NBE, B, 0, stream>>>(src, dst, tile_cursor, brec);
        k_tdeg  <<<NT, 512, 0, stream>>>(brec, tile_base, tile_counts, dinv);
        k_xw    <<<(NN + B - 1) / B, B, 0, stream>>>(x, W1, dinv, g1);
        k_agg1t <<<NT, 512, 0, stream>>>(brec, tile_base, tile_counts, g1, dinv, b1, W2, g2);
        k_agg2t <<<NT, 512, 0, stream>>>(brec, tile_base, tile_counts, g2, dinv, b2, out);
        return;
    }

    // -------- fallback: atomic-scatter path (needs 38N floats) --------------
    char* wsb = (char*)d_ws;
    int*   deg  = (int*)wsb;
    float* acc1 = (float*)(wsb + (size_t)NN * 4);
    float* acc2 = (float*)(wsb + (size_t)17 * NN * 4);
    float* dinv = (float*)(wsb + (size_t)19 * NN * 4);
    float* g1   = (float*)(wsb + (size_t)20 * NN * 4);
    float* g2   = (float*)(wsb + (size_t)36 * NN * 4);

    hipMemsetAsync(d_ws, 0, (size_t)19 * NN * 4, stream);

    int gN = (NN + B - 1) / B, gE = (EE + B - 1) / B, gE4 = (EE * 4 + B - 1) / B;
    k_deg_f     <<<gE, B, 0, stream>>>(dst, deg);
    k_dinv_f    <<<gN, B, 0, stream>>>(deg, dinv);
    k_xw        <<<gN, B, 0, stream>>>(x, W1, dinv, g1);
    k_scatter1_f<<<gE4, B, 0, stream>>>(src, dst, g1, acc1);
    k_l2_f      <<<gN, B, 0, stream>>>(g1, acc1, dinv, b1, W2, g2);
    k_scatter2_f<<<gE, B, 0, stream>>>(src, dst, g2, acc2);
    k_final_f   <<<gN, B, 0, stream>>>(g2, acc2, dinv, b2, out);
}

// Round 5
// 1125.648 us; speedup vs baseline: 2.0688x; 1.0104x over previous
//
#include <hip/hip_runtime.h>

#define NN   200000
#define EE   6400000
#define INC  128
#define HIDC 16
#define OUTC 2

#define TN     256                 // nodes per dst tile
#define TSHIFT 8
#define TMASK  (TN - 1)
#define NT     782                 // ceil(NN / TN)
#define CHUNK  8192                // edges per hist/place block
#define NBE    782                 // ceil(EE / CHUNK)
#define SP1    17                  // padded LDS stride, layer-1 acc
#define SP2    3                   // padded LDS stride, layer-2 acc
#define NSUBMAX 4
#define NBMAX  (NT * NSUBMAX)      // 3128 buckets max

// bucket id = (dst>>8)*nsub + min(src>>16, nsub-1)
__device__ __forceinline__ int bucket_of(int s, int d, int nsub) {
    int q = s >> 16;
    int qm = nsub - 1;
    q = (q > qm) ? qm : q;
    return (d >> TSHIFT) * nsub + q;
}

// ---------------- histogram over (dst-tile, src-range) buckets --------------
__global__ __launch_bounds__(256) void k_hist(const int* __restrict__ src,
                                              const int* __restrict__ dst,
                                              int* __restrict__ bkt_counts,
                                              int nsub) {
    __shared__ int h[NBMAX];
    int nb = NT * nsub;
    for (int t = threadIdx.x; t < nb; t += 256) h[t] = 0;
    __syncthreads();
    int base = blockIdx.x * CHUNK;
    if (base + CHUNK <= EE) {
        for (int i = threadIdx.x; i < CHUNK; i += 1024) {
            int e = base + i;
            int b0 = bucket_of(src[e],       dst[e],       nsub);
            int b1 = bucket_of(src[e + 256], dst[e + 256], nsub);
            int b2 = bucket_of(src[e + 512], dst[e + 512], nsub);
            int b3 = bucket_of(src[e + 768], dst[e + 768], nsub);
            atomicAdd(&h[b0], 1);
            atomicAdd(&h[b1], 1);
            atomicAdd(&h[b2], 1);
            atomicAdd(&h[b3], 1);
        }
    } else {
        for (int i = threadIdx.x; i < CHUNK; i += 256) {
            int e = base + i;
            if (e < EE) atomicAdd(&h[bucket_of(src[e], dst[e], nsub)], 1);
        }
    }
    __syncthreads();
    for (int t = threadIdx.x; t < nb; t += 256)
        if (h[t]) atomicAdd(&bkt_counts[t], h[t]);
}

// ---------------- exclusive scan of bucket counts (single block) ------------
// thread t owns buckets [4t, 4t+4)
__global__ __launch_bounds__(1024) void k_scan(const int* __restrict__ bkt_counts,
                                               int* __restrict__ bkt_base,
                                               int* __restrict__ bkt_cursor,
                                               int nb) {
    __shared__ int tmp[1024];
    int t = threadIdx.x;
    int v[4]; int s = 0;
#pragma unroll
    for (int j = 0; j < 4; ++j) {
        int b = t * 4 + j;
        v[j] = (b < nb) ? bkt_counts[b] : 0;
        s += v[j];
    }
    tmp[t] = s;
    __syncthreads();
    for (int o = 1; o < 1024; o <<= 1) {
        int u = (t >= o) ? tmp[t - o] : 0;
        __syncthreads();
        tmp[t] += u;
        __syncthreads();
    }
    int ex = tmp[t] - s;
#pragma unroll
    for (int j = 0; j < 4; ++j) {
        int b = t * 4 + j;
        if (b < nb) { bkt_base[b] = ex; bkt_cursor[b] = ex; }
        ex += v[j];
    }
}

// ---------------- place edges into buckets ----------------------------------
// record = (src << 8) | (dst & 255)
__global__ __launch_bounds__(256) void k_bplace(const int* __restrict__ src,
                                                const int* __restrict__ dst,
                                                int* __restrict__ bkt_cursor,
                                                int* __restrict__ brec,
                                                int nsub) {
    __shared__ int h[NBMAX];
    __shared__ int lcur[NBMAX];
    int nb = NT * nsub;
    for (int t = threadIdx.x; t < nb; t += 256) h[t] = 0;
    __syncthreads();
    int base = blockIdx.x * CHUNK;
    bool full = (base + CHUNK <= EE);
    if (full) {
        for (int i = threadIdx.x; i < CHUNK; i += 1024) {
            int e = base + i;
            atomicAdd(&h[bucket_of(src[e],       dst[e],       nsub)], 1);
            atomicAdd(&h[bucket_of(src[e + 256], dst[e + 256], nsub)], 1);
            atomicAdd(&h[bucket_of(src[e + 512], dst[e + 512], nsub)], 1);
            atomicAdd(&h[bucket_of(src[e + 768], dst[e + 768], nsub)], 1);
        }
    } else {
        for (int i = threadIdx.x; i < CHUNK; i += 256) {
            int e = base + i;
            if (e < EE) atomicAdd(&h[bucket_of(src[e], dst[e], nsub)], 1);
        }
    }
    __syncthreads();
    for (int t = threadIdx.x; t < nb; t += 256) {
        int c = h[t];
        lcur[t] = c ? atomicAdd(&bkt_cursor[t], c) : 0;
    }
    __syncthreads();
    if (full) {
        for (int i = threadIdx.x; i < CHUNK; i += 1024) {
            int e = base + i;
            int d0 = dst[e], d1 = dst[e + 256], d2 = dst[e + 512], d3 = dst[e + 768];
            int s0 = src[e], s1 = src[e + 256], s2 = src[e + 512], s3 = src[e + 768];
            int p0 = atomicAdd(&lcur[bucket_of(s0, d0, nsub)], 1);
            int p1 = atomicAdd(&lcur[bucket_of(s1, d1, nsub)], 1);
            int p2 = atomicAdd(&lcur[bucket_of(s2, d2, nsub)], 1);
            int p3 = atomicAdd(&lcur[bucket_of(s3, d3, nsub)], 1);
            brec[p0] = (s0 << 8) | (d0 & TMASK);
            brec[p1] = (s1 << 8) | (d1 & TMASK);
            brec[p2] = (s2 << 8) | (d2 & TMASK);
            brec[p3] = (s3 << 8) | (d3 & TMASK);
        }
    } else {
        for (int i = threadIdx.x; i < CHUNK; i += 256) {
            int e = base + i;
            if (e < EE) {
                int d = dst[e], s = src[e];
                int pos = atomicAdd(&lcur[bucket_of(s, d, nsub)], 1);
                brec[pos] = (s << 8) | (d & TMASK);
            }
        }
    }
}

// ---------------- per-tile degree -> dinv -----------------------------------
__global__ __launch_bounds__(512) void k_tdeg(const int* __restrict__ brec,
                                              const int* __restrict__ bkt_base,
                                              const int* __restrict__ bkt_counts,
                                              float* __restrict__ dinv,
                                              int nsub) {
    __shared__ int degs[TN];
    int t = blockIdx.x;
    if (threadIdx.x < TN) degs[threadIdx.x] = 0;
    __syncthreads();
    int s0 = bkt_base[t * nsub];
    int cnt = 0;
    for (int q = 0; q < nsub; ++q) cnt += bkt_counts[t * nsub + q];
    int i = threadIdx.x;
    for (; i + 1536 < cnt; i += 2048) {
        int r0 = brec[s0 + i];
        int r1 = brec[s0 + i + 512];
        int r2 = brec[s0 + i + 1024];
        int r3 = brec[s0 + i + 1536];
        atomicAdd(&degs[r0 & TMASK], 1);
        atomicAdd(&degs[r1 & TMASK], 1);
        atomicAdd(&degs[r2 & TMASK], 1);
        atomicAdd(&degs[r3 & TMASK], 1);
    }
    for (; i < cnt; i += 512) atomicAdd(&degs[brec[s0 + i] & TMASK], 1);
    __syncthreads();
    int node = t * TN + threadIdx.x;
    if (threadIdx.x < TN && node < NN)
        dinv[node] = rsqrtf((float)(degs[threadIdx.x] + 1));   // +1 = self-loop
}

// ---------------- g1 = dinv * (x @ W1) --------------------------------------
__global__ __launch_bounds__(256) void k_xw(const float* __restrict__ x,
                                            const float* __restrict__ W1,
                                            const float* __restrict__ dinv,
                                            float* __restrict__ g1) {
    __shared__ float Ws[INC * HIDC];           // 8 KB
    for (int j = threadIdx.x; j < INC * HIDC; j += 256) Ws[j] = W1[j];
    __syncthreads();
    int n = blockIdx.x * 256 + threadIdx.x;
    if (n >= NN) return;
    const float4* xr = (const float4*)(x + (size_t)n * INC);
    float acc[HIDC];
#pragma unroll
    for (int c = 0; c < HIDC; ++c) acc[c] = 0.f;
    for (int k4 = 0; k4 < INC / 4; ++k4) {
        float4 xv = xr[k4];
        const float* w0 = &Ws[(k4 * 4) * HIDC];
        float xs[4] = {xv.x, xv.y, xv.z, xv.w};
#pragma unroll
        for (int j = 0; j < 4; ++j) {
#pragma unroll
            for (int c = 0; c < HIDC; ++c) acc[c] += xs[j] * w0[j * HIDC + c];
        }
    }
    float dn = dinv[n];
    float4* gout = (float4*)(g1 + (size_t)n * HIDC);
#pragma unroll
    for (int q = 0; q < 4; ++q) {
        float4 v;
        v.x = dn * acc[q * 4 + 0];
        v.y = dn * acc[q * 4 + 1];
        v.z = dn * acc[q * 4 + 2];
        v.w = dn * acc[q * 4 + 3];
        gout[q] = v;
    }
}

// ---------------- layer-1 aggregate, phased by src range --------------------
// All blocks walk q = 0..nsub-1 in order, so the active g1 slice (<=4 MB)
// stays resident in each XCD's L2.
__global__ __launch_bounds__(512) void k_agg1t(const int* __restrict__ brec,
                                               const int* __restrict__ bkt_base,
                                               const int* __restrict__ bkt_counts,
                                               const float* __restrict__ g1,
                                               const float* __restrict__ dinv,
                                               const float* __restrict__ b1,
                                               const float* __restrict__ W2,
                                               float* __restrict__ g2,
                                               int nsub) {
    __shared__ float acc[TN * SP1];            // 17 KB
    int t = blockIdx.x;
    for (int i = threadIdx.x; i < TN * SP1; i += 512) acc[i] = 0.f;
    __syncthreads();
    for (int q = 0; q < nsub; ++q) {
        int s0 = bkt_base[t * nsub + q];
        int cnt = bkt_counts[t * nsub + q];
        int i = threadIdx.x;
        for (; i + 512 < cnt; i += 1024) {     // unroll x2: 8 gathers in flight
            int r0 = brec[s0 + i];
            int r1 = brec[s0 + i + 512];
            const float4* p0 = (const float4*)g1 + (size_t)(r0 >> 8) * 4;
            const float4* p1 = (const float4*)g1 + (size_t)(r1 >> 8) * 4;
            float4 a0 = p0[0], a1 = p0[1], a2 = p0[2], a3 = p0[3];
            float4 c0 = p1[0], c1 = p1[1], c2 = p1[2], c3 = p1[3];
            float* d0 = &acc[(r0 & TMASK) * SP1];
            float* d1 = &acc[(r1 & TMASK) * SP1];
            atomicAdd(d0 + 0,  a0.x); atomicAdd(d0 + 1,  a0.y);
            atomicAdd(d0 + 2,  a0.z); atomicAdd(d0 + 3,  a0.w);
            atomicAdd(d0 + 4,  a1.x); atomicAdd(d0 + 5,  a1.y);
            atomicAdd(d0 + 6,  a1.z); atomicAdd(d0 + 7,  a1.w);
            atomicAdd(d0 + 8,  a2.x); atomicAdd(d0 + 9,  a2.y);
            atomicAdd(d0 + 10, a2.z); atomicAdd(d0 + 11, a2.w);
            atomicAdd(d0 + 12, a3.x); atomicAdd(d0 + 13, a3.y);
            atomicAdd(d0 + 14, a3.z); atomicAdd(d0 + 15, a3.w);
            atomicAdd(d1 + 0,  c0.x); atomicAdd(d1 + 1,  c0.y);
            atomicAdd(d1 + 2,  c0.z); atomicAdd(d1 + 3,  c0.w);
            atomicAdd(d1 + 4,  c1.x); atomicAdd(d1 + 5,  c1.y);
            atomicAdd(d1 + 6,  c1.z); atomicAdd(d1 + 7,  c1.w);
            atomicAdd(d1 + 8,  c2.x); atomicAdd(d1 + 9,  c2.y);
            atomicAdd(d1 + 10, c2.z); atomicAdd(d1 + 11, c2.w);
            atomicAdd(d1 + 12, c3.x); atomicAdd(d1 + 13, c3.y);
            atomicAdd(d1 + 14, c3.z); atomicAdd(d1 + 15, c3.w);
        }
        for (; i < cnt; i += 512) {
            int r0 = brec[s0 + i];
            const float4* p0 = (const float4*)g1 + (size_t)(r0 >> 8) * 4;
            float4 a0 = p0[0], a1 = p0[1], a2 = p0[2], a3 = p0[3];
            float* d0 = &acc[(r0 & TMASK) * SP1];
            atomicAdd(d0 + 0,  a0.x); atomicAdd(d0 + 1,  a0.y);
            atomicAdd(d0 + 2,  a0.z); atomicAdd(d0 + 3,  a0.w);
            atomicAdd(d0 + 4,  a1.x); atomicAdd(d0 + 5,  a1.y);
            atomicAdd(d0 + 6,  a1.z); atomicAdd(d0 + 7,  a1.w);
            atomicAdd(d0 + 8,  a2.x); atomicAdd(d0 + 9,  a2.y);
            atomicAdd(d0 + 10, a2.z); atomicAdd(d0 + 11, a2.w);
            atomicAdd(d0 + 12, a3.x); atomicAdd(d0 + 13, a3.y);
            atomicAdd(d0 + 14, a3.z); atomicAdd(d0 + 15, a3.w);
        }
    }
    __syncthreads();
    int lane = threadIdx.x & 15;
    int nb = t * TN;
    for (int nn = threadIdx.x >> 4; nn < TN; nn += 32) {
        int node = nb + nn;
        if (node < NN) {                       // uniform across the 16-lane group
            float a = acc[nn * SP1 + lane];
            float self = g1[(size_t)node * HIDC + lane];
            float dn = dinv[node];
            float h = fmaxf(fmaf(dn, a + self, b1[lane]), 0.f);
            float p0 = h * W2[lane * OUTC + 0];
            float p1 = h * W2[lane * OUTC + 1];
#pragma unroll
            for (int o = 8; o; o >>= 1) {
                p0 += __shfl_xor(p0, o, 16);
                p1 += __shfl_xor(p1, o, 16);
            }
            if (lane == 0) {
                float2 v; v.x = dn * p0; v.y = dn * p1;
                ((float2*)g2)[node] = v;
            }
        }
    }
}

// ---------------- layer-2 aggregate + final epilogue ------------------------
// g2 table is 1.6 MB -> fully L2 resident; treat tile's buckets as one range.
__global__ __launch_bounds__(512) void k_agg2t(const int* __restrict__ brec,
                                               const int* __restrict__ bkt_base,
                                               const int* __restrict__ bkt_counts,
                                               const float* __restrict__ g2,
                                               const float* __restrict__ dinv,
                                               const float* __restrict__ b2,
                                               float* __restrict__ out,
                                               int nsub) {
    __shared__ float acc[TN * SP2];            // 3 KB, stride-3 padded
    int t = blockIdx.x;
    for (int i = threadIdx.x; i < TN * SP2; i += 512) acc[i] = 0.f;
    __syncthreads();
    int s0 = bkt_base[t * nsub];
    int cnt = 0;
    for (int q = 0; q < nsub; ++q) cnt += bkt_counts[t * nsub + q];
    int i = threadIdx.x;
    for (; i + 1536 < cnt; i += 2048) {        // unroll x4
        int r0 = brec[s0 + i];
        int r1 = brec[s0 + i + 512];
        int r2 = brec[s0 + i + 1024];
        int r3 = brec[s0 + i + 1536];
        float2 v0 = ((const float2*)g2)[r0 >> 8];
        float2 v1 = ((const float2*)g2)[r1 >> 8];
        float2 v2 = ((const float2*)g2)[r2 >> 8];
        float2 v3 = ((const float2*)g2)[r3 >> 8];
        atomicAdd(&acc[(r0 & TMASK) * SP2 + 0], v0.x);
        atomicAdd(&acc[(r0 & TMASK) * SP2 + 1], v0.y);
        atomicAdd(&acc[(r1 & TMASK) * SP2 + 0], v1.x);
        atomicAdd(&acc[(r1 & TMASK) * SP2 + 1], v1.y);
        atomicAdd(&acc[(r2 & TMASK) * SP2 + 0], v2.x);
        atomicAdd(&acc[(r2 & TMASK) * SP2 + 1], v2.y);
        atomicAdd(&acc[(r3 & TMASK) * SP2 + 0], v3.x);
        atomicAdd(&acc[(r3 & TMASK) * SP2 + 1], v3.y);
    }
    for (; i < cnt; i += 512) {
        int r0 = brec[s0 + i];
        float2 v0 = ((const float2*)g2)[r0 >> 8];
        atomicAdd(&acc[(r0 & TMASK) * SP2 + 0], v0.x);
        atomicAdd(&acc[(r0 & TMASK) * SP2 + 1], v0.y);
    }
    __syncthreads();
    int node = t * TN + threadIdx.x;
    if (threadIdx.x < TN && node < NN) {
        float dn = dinv[node];
        float2 g = ((const float2*)g2)[node];
        float2 o;
        o.x = fmaf(dn, acc[threadIdx.x * SP2 + 0] + g.x, b2[0]);
        o.y = fmaf(dn, acc[threadIdx.x * SP2 + 1] + g.y, b2[1]);
        ((float2*)out)[node] = o;
    }
}

// ======================= fallback (atomic scatter) kernels ==================

__global__ void k_deg_f(const int* __restrict__ dst, int* __restrict__ deg) {
    int i = blockIdx.x * blockDim.x + threadIdx.x;
    if (i < EE) atomicAdd(&deg[dst[i]], 1);
}
__global__ void k_dinv_f(const int* __restrict__ deg, float* __restrict__ dinv) {
    int n = blockIdx.x * blockDim.x + threadIdx.x;
    if (n < NN) dinv[n] = rsqrtf((float)(deg[n] + 1));
}
__global__ void k_scatter1_f(const int* __restrict__ src, const int* __restrict__ dst,
                             const float* __restrict__ g1, float* __restrict__ acc1) {
    int i = blockIdx.x * blockDim.x + threadIdx.x;
    if (i >= EE * 4) return;
    int e = i >> 2, q = i & 3;
    float4 v = ((const float4*)g1)[src[e] * 4 + q];
    float* p = acc1 + (size_t)dst[e] * HIDC + q * 4;
    unsafeAtomicAdd(p + 0, v.x); unsafeAtomicAdd(p + 1, v.y);
    unsafeAtomicAdd(p + 2, v.z); unsafeAtomicAdd(p + 3, v.w);
}
__global__ void k_l2_f(const float* __restrict__ g1, const float* __restrict__ acc1,
                       const float* __restrict__ dinv, const float* __restrict__ b1,
                       const float* __restrict__ W2, float* __restrict__ g2) {
    int n = blockIdx.x * blockDim.x + threadIdx.x;
    if (n >= NN) return;
    float dn = dinv[n];
    float h[HIDC];
#pragma unroll
    for (int c = 0; c < HIDC; ++c)
        h[c] = fmaxf(dn * (acc1[(size_t)n * HIDC + c] + g1[(size_t)n * HIDC + c]) + b1[c], 0.f);
    float o0 = 0.f, o1 = 0.f;
#pragma unroll
    for (int c = 0; c < HIDC; ++c) { o0 += h[c] * W2[c * 2]; o1 += h[c] * W2[c * 2 + 1]; }
    g2[(size_t)n * 2] = dn * o0; g2[(size_t)n * 2 + 1] = dn * o1;
}
__global__ void k_scatter2_f(const int* __restrict__ src, const int* __restrict__ dst,
                             const float* __restrict__ g2, float* __restrict__ acc2) {
    int e = blockIdx.x * blockDim.x + threadIdx.x;
    if (e >= EE) return;
    float2 v = ((const float2*)g2)[src[e]];
    unsafeAtomicAdd(&acc2[(size_t)dst[e] * 2], v.x);
    unsafeAtomicAdd(&acc2[(size_t)dst[e] * 2 + 1], v.y);
}
__global__ void k_final_f(const float* __restrict__ g2, const float* __restrict__ acc2,
                          const float* __restrict__ dinv, const float* __restrict__ b2,
                          float* __restrict__ out) {
    int n = blockIdx.x * blockDim.x + threadIdx.x;
    if (n >= NN) return;
    float dn = dinv[n];
    float2 a = ((const float2*)acc2)[n];
    float2 g = ((const float2*)g2)[n];
    float2 o;
    o.x = dn * (a.x + g.x) + b2[0];
    o.y = dn * (a.y + g.y) + b2[1];
    ((float2*)out)[n] = o;
}

// ======================= launch =============================================

static void launch_tiled(const float* x, const int* src, const int* dst,
                         const float* W1, const float* b1,
                         const float* W2, const float* b2,
                         float* out, void* d_ws, int nsub, hipStream_t stream) {
    int nb = NT * nsub;
    int* ws          = (int*)d_ws;
    int* bkt_counts  = ws;
    int* bkt_base    = ws + NBMAX;
    int* bkt_cursor  = ws + 2 * NBMAX;
    int* brec        = ws + 3 * NBMAX;
    float* dinv      = (float*)(ws + 3 * NBMAX + EE);
    float* g1        = dinv + NN;
    float* g2        = g1 + (size_t)NN * HIDC;

    hipMemsetAsync(bkt_counts, 0, (size_t)nb * 4, stream);

    k_hist  <<<NBE, 256, 0, stream>>>(src, dst, bkt_counts, nsub);
    k_scan  <<<1, 1024, 0, stream>>>(bkt_counts, bkt_base, bkt_cursor, nb);
    k_bplace<<<NBE, 256, 0, stream>>>(src, dst, bkt_cursor, brec, nsub);
    k_tdeg  <<<NT, 512, 0, stream>>>(brec, bkt_base, bkt_counts, dinv, nsub);
    k_xw    <<<(NN + 255) / 256, 256, 0, stream>>>(x, W1, dinv, g1);
    k_agg1t <<<NT, 512, 0, stream>>>(brec, bkt_base, bkt_counts, g1, dinv, b1, W2, g2, nsub);
    k_agg2t <<<NT, 512, 0, stream>>>(brec, bkt_base, bkt_counts, g2, dinv, b2, out, nsub);
}

extern "C" void kernel_launch(void* const* d_in, const int* in_sizes, int n_in,
                              void* d_out, int out_size, void* d_ws, size_t ws_size,
                              hipStream_t stream) {
    const float* x  = (const float*)d_in[0];
    const int*   ei = (const int*)d_in[1];     // [2, E] flat: src then dst
    const float* W1 = (const float*)d_in[2];
    const float* b1 = (const float*)d_in[3];
    const float* W2 = (const float*)d_in[4];
    const float* b2 = (const float*)d_in[5];
    float* out = (float*)d_out;

    const int* src = ei;
    const int* dst = ei + EE;
    const int B = 256;

    size_t need4 = ((size_t)3 * NBMAX + EE + (size_t)19 * NN) * 4;
    if (ws_size >= need4) {
        launch_tiled(x, src, dst, W1, b1, W2, b2, out, d_ws, NSUBMAX, stream);
        return;
    }
    size_t need1 = ((size_t)3 * NBMAX + EE + (size_t)19 * NN) * 4; // same layout
    if (ws_size >= need1) {
        launch_tiled(x, src, dst, W1, b1, W2, b2, out, d_ws, 1, stream);
        return;
    }

    // -------- fallback: atomic-scatter path (needs 38N floats) --------------
    char* wsb = (char*)d_ws;
    int*   deg  = (int*)wsb;
    float* acc1 = (float*)(wsb + (size_t)NN * 4);
    float* acc2 = (float*)(wsb + (size_t)17 * NN * 4);
    float* dinv = (float*)(wsb + (size_t)19 * NN * 4);
    float* g1   = (float*)(wsb + (size_t)20 * NN * 4);
    float* g2   = (float*)(wsb + (size_t)36 * NN * 4);

    hipMemsetAsync(d_ws, 0, (size_t)19 * NN * 4, stream);

    int gN = (NN + B - 1) / B, gE = (EE + B - 1) / B, gE4 = (EE * 4 + B - 1) / B;
    k_deg_f     <<<gE, B, 0, stream>>>(dst, deg);
    k_dinv_f    <<<gN, B, 0, stream>>>(deg, dinv);
    k_xw        <<<gN, B, 0, stream>>>(x, W1, dinv, g1);
    k_scatter1_f<<<gE4, B, 0, stream>>>(src, dst, g1, acc1);
    k_l2_f      <<<gN, B, 0, stream>>>(g1, acc1, dinv, b1, W2, g2);
    k_scatter2_f<<<gE, B, 0, stream>>>(src, dst, g2, acc2);
    k_final_f   <<<gN, B, 0, stream>>>(g2, acc2, dinv, b2, out);
}

// Round 6
// 579.017 us; speedup vs baseline: 4.0220x; 1.9441x over previous
//
#include <hip/hip_runtime.h>

#define NN   200000
#define EE   6400000
#define INC  128
#define HIDC 16
#define OUTC 2

#define TN     256                 // nodes per dst tile
#define TSHIFT 8
#define TMASK  (TN - 1)
#define NT     782                 // ceil(NN / TN)
#define CHUNK  8192                // edges per hist/place block
#define NBE    782                 // ceil(EE / CHUNK)
#define SCAP   10240               // per-tile record capacity (mean 8192, +22 sigma)

// ---------------- histogram over dst tiles ----------------------------------
__global__ __launch_bounds__(256) void k_hist(const int* __restrict__ dst,
                                              int* __restrict__ tile_counts) {
    __shared__ int h[NT];
    for (int t = threadIdx.x; t < NT; t += 256) h[t] = 0;
    __syncthreads();
    int base = blockIdx.x * CHUNK;
    if (base + CHUNK <= EE) {
        for (int i = threadIdx.x; i < CHUNK; i += 1024) {
            int d0 = dst[base + i];
            int d1 = dst[base + i + 256];
            int d2 = dst[base + i + 512];
            int d3 = dst[base + i + 768];
            atomicAdd(&h[d0 >> TSHIFT], 1);
            atomicAdd(&h[d1 >> TSHIFT], 1);
            atomicAdd(&h[d2 >> TSHIFT], 1);
            atomicAdd(&h[d3 >> TSHIFT], 1);
        }
    } else {
        for (int i = threadIdx.x; i < CHUNK; i += 256) {
            int e = base + i;
            if (e < EE) atomicAdd(&h[dst[e] >> TSHIFT], 1);
        }
    }
    __syncthreads();
    for (int t = threadIdx.x; t < NT; t += 256)
        if (h[t]) atomicAdd(&tile_counts[t], h[t]);
}

// ---------------- exclusive scan of tile counts (single block) --------------
__global__ __launch_bounds__(1024) void k_scan(const int* __restrict__ tile_counts,
                                               int* __restrict__ tile_base,
                                               int* __restrict__ tile_cursor,
                                               int* __restrict__ nstart) {
    __shared__ int tmp[1024];
    int t = threadIdx.x;
    int v = (t < NT) ? tile_counts[t] : 0;
    tmp[t] = v;
    __syncthreads();
    for (int o = 1; o < 1024; o <<= 1) {
        int u = (t >= o) ? tmp[t - o] : 0;
        __syncthreads();
        tmp[t] += u;
        __syncthreads();
    }
    if (t < NT) {
        int ex = tmp[t] - v;
        tile_base[t] = ex;
        tile_cursor[t] = ex;
    }
    if (t == 0) nstart[NN] = EE;               // sentinel for deg of last node
}

// ---------------- place edges into tile buckets -----------------------------
// record = (src << 8) | (dst & 255)
__global__ __launch_bounds__(256) void k_bplace(const int* __restrict__ src,
                                                const int* __restrict__ dst,
                                                int* __restrict__ tile_cursor,
                                                int* __restrict__ brec) {
    __shared__ int h[NT];
    __shared__ int lcur[NT];
    for (int t = threadIdx.x; t < NT; t += 256) h[t] = 0;
    __syncthreads();
    int base = blockIdx.x * CHUNK;
    bool full = (base + CHUNK <= EE);
    if (full) {
        for (int i = threadIdx.x; i < CHUNK; i += 1024) {
            int e = base + i;
            atomicAdd(&h[dst[e] >> TSHIFT], 1);
            atomicAdd(&h[dst[e + 256] >> TSHIFT], 1);
            atomicAdd(&h[dst[e + 512] >> TSHIFT], 1);
            atomicAdd(&h[dst[e + 768] >> TSHIFT], 1);
        }
    } else {
        for (int i = threadIdx.x; i < CHUNK; i += 256) {
            int e = base + i;
            if (e < EE) atomicAdd(&h[dst[e] >> TSHIFT], 1);
        }
    }
    __syncthreads();
    for (int t = threadIdx.x; t < NT; t += 256) {
        int c = h[t];
        lcur[t] = c ? atomicAdd(&tile_cursor[t], c) : 0;
    }
    __syncthreads();
    if (full) {
        for (int i = threadIdx.x; i < CHUNK; i += 1024) {
            int e = base + i;
            int d0 = dst[e], d1 = dst[e + 256], d2 = dst[e + 512], d3 = dst[e + 768];
            int s0 = src[e], s1 = src[e + 256], s2 = src[e + 512], s3 = src[e + 768];
            int p0 = atomicAdd(&lcur[d0 >> TSHIFT], 1);
            int p1 = atomicAdd(&lcur[d1 >> TSHIFT], 1);
            int p2 = atomicAdd(&lcur[d2 >> TSHIFT], 1);
            int p3 = atomicAdd(&lcur[d3 >> TSHIFT], 1);
            brec[p0] = (s0 << 8) | (d0 & TMASK);
            brec[p1] = (s1 << 8) | (d1 & TMASK);
            brec[p2] = (s2 << 8) | (d2 & TMASK);
            brec[p3] = (s3 << 8) | (d3 & TMASK);
        }
    } else {
        for (int i = threadIdx.x; i < CHUNK; i += 256) {
            int e = base + i;
            if (e < EE) {
                int d = dst[e], s = src[e];
                int pos = atomicAdd(&lcur[d >> TSHIFT], 1);
                brec[pos] = (s << 8) | (d & TMASK);
            }
        }
    }
}

// ---------------- per-tile counting sort -> node-sorted CSR (in place) ------
// Buffers the tile's records in LDS, histograms by local node, scans, then
// rewrites the SAME global segment in node-sorted order (src ids only).
// Also emits nstart[node] = absolute row start. brec becomes the CSR.
__global__ __launch_bounds__(256) void k_sortt(int* __restrict__ brec,
                                               const int* __restrict__ tile_base,
                                               const int* __restrict__ tile_counts,
                                               int* __restrict__ nstart) {
    __shared__ int rec[SCAP];                  // 40 KB
    __shared__ int hist[TN];
    __shared__ int scn[TN];
    __shared__ int cur[TN];
    int t = blockIdx.x;
    int s0 = tile_base[t];
    int cnt = tile_counts[t];
    if (cnt > SCAP) cnt = SCAP;                // deterministic input: never hit
    if (threadIdx.x < TN) hist[threadIdx.x] = 0;
    __syncthreads();
    for (int i = threadIdx.x; i < cnt; i += 256) {
        int r = brec[s0 + i];
        rec[i] = r;
        atomicAdd(&hist[r & TMASK], 1);
    }
    __syncthreads();
    // inclusive scan of hist -> scn
    if (threadIdx.x < TN) scn[threadIdx.x] = hist[threadIdx.x];
    __syncthreads();
    for (int o = 1; o < TN; o <<= 1) {
        int u = (threadIdx.x >= o && threadIdx.x < TN) ? scn[threadIdx.x - o] : 0;
        __syncthreads();
        if (threadIdx.x < TN) scn[threadIdx.x] += u;
        __syncthreads();
    }
    if (threadIdx.x < TN) {
        int ex = scn[threadIdx.x] - hist[threadIdx.x];
        cur[threadIdx.x] = ex;
        int node = t * TN + threadIdx.x;
        if (node < NN) nstart[node] = s0 + ex;
    }
    __syncthreads();
    for (int i = threadIdx.x; i < cnt; i += 256) {
        int r = rec[i];
        int pos = atomicAdd(&cur[r & TMASK], 1);
        brec[s0 + pos] = r >> 8;               // store src id, node-sorted
    }
}

// ---------------- g1 = dinv * (x @ W1) --------------------------------------
__global__ __launch_bounds__(256) void k_xw(const float* __restrict__ x,
                                            const float* __restrict__ W1,
                                            const int* __restrict__ nstart,
                                            float* __restrict__ g1) {
    __shared__ float Ws[INC * HIDC];           // 8 KB
    for (int j = threadIdx.x; j < INC * HIDC; j += 256) Ws[j] = W1[j];
    __syncthreads();
    int n = blockIdx.x * 256 + threadIdx.x;
    if (n >= NN) return;
    const float4* xr = (const float4*)(x + (size_t)n * INC);
    float acc[HIDC];
#pragma unroll
    for (int c = 0; c < HIDC; ++c) acc[c] = 0.f;
    for (int k4 = 0; k4 < INC / 4; ++k4) {
        float4 xv = xr[k4];
        const float* w0 = &Ws[(k4 * 4) * HIDC];
        float xs[4] = {xv.x, xv.y, xv.z, xv.w};
#pragma unroll
        for (int j = 0; j < 4; ++j) {
#pragma unroll
            for (int c = 0; c < HIDC; ++c) acc[c] += xs[j] * w0[j * HIDC + c];
        }
    }
    float dn = rsqrtf((float)(nstart[n + 1] - nstart[n] + 1));   // +1 self-loop
    float4* gout = (float4*)(g1 + (size_t)n * HIDC);
#pragma unroll
    for (int q = 0; q < 4; ++q) {
        float4 v;
        v.x = dn * acc[q * 4 + 0];
        v.y = dn * acc[q * 4 + 1];
        v.z = dn * acc[q * 4 + 2];
        v.w = dn * acc[q * 4 + 3];
        gout[q] = v;
    }
}

// ---------------- layer-1 gather + fused MLP (no atomics) -------------------
// 16 lanes per node, lane = hidden channel; one coalesced 64 B row per edge.
// g2[n] = dinv[n] * ( relu( dinv[n]*(sum g1[s] + g1[n]) + b1 ) @ W2 )
__global__ __launch_bounds__(256) void k_agg1n(const int* __restrict__ csr,
                                               const int* __restrict__ nstart,
                                               const float* __restrict__ g1,
                                               const float* __restrict__ b1,
                                               const float* __restrict__ W2,
                                               float* __restrict__ g2) {
    int lane = threadIdx.x & 15;
    int n = (blockIdx.x * 256 + threadIdx.x) >> 4;
    if (n >= NN) return;
    int rs = nstart[n], re = nstart[n + 1];
    float dn = rsqrtf((float)(re - rs + 1));
    float acc = g1[(size_t)n * HIDC + lane];   // self-loop
    int i = rs;
    for (; i + 4 <= re; i += 4) {              // 4 row-loads in flight
        int s0 = csr[i], s1 = csr[i + 1], s2 = csr[i + 2], s3 = csr[i + 3];
        float v0 = g1[(size_t)s0 * HIDC + lane];
        float v1 = g1[(size_t)s1 * HIDC + lane];
        float v2 = g1[(size_t)s2 * HIDC + lane];
        float v3 = g1[(size_t)s3 * HIDC + lane];
        acc += v0 + v1 + v2 + v3;
    }
    for (; i < re; ++i) acc += g1[(size_t)csr[i] * HIDC + lane];
    float h = fmaxf(fmaf(dn, acc, b1[lane]), 0.f);
    float p0 = h * W2[lane * OUTC + 0];
    float p1 = h * W2[lane * OUTC + 1];
#pragma unroll
    for (int o = 8; o; o >>= 1) {
        p0 += __shfl_xor(p0, o, 16);
        p1 += __shfl_xor(p1, o, 16);
    }
    if (lane == 0) {
        float2 v; v.x = dn * p0; v.y = dn * p1;
        ((float2*)g2)[n] = v;
    }
}

// ---------------- layer-2 gather + final epilogue (no atomics) --------------
__global__ __launch_bounds__(256) void k_agg2n(const int* __restrict__ csr,
                                               const int* __restrict__ nstart,
                                               const float* __restrict__ g2,
                                               const float* __restrict__ b2,
                                               float* __restrict__ out) {
    int lane = threadIdx.x & 7;
    int n = (blockIdx.x * 256 + threadIdx.x) >> 3;
    if (n >= NN) return;
    int rs = nstart[n], re = nstart[n + 1];
    float dn = rsqrtf((float)(re - rs + 1));
    float ax = 0.f, ay = 0.f;
    for (int i = rs + lane; i < re; i += 8) {
        float2 v = ((const float2*)g2)[csr[i]];
        ax += v.x; ay += v.y;
    }
#pragma unroll
    for (int o = 4; o; o >>= 1) {
        ax += __shfl_xor(ax, o, 8);
        ay += __shfl_xor(ay, o, 8);
    }
    if (lane == 0) {
        float2 g = ((const float2*)g2)[n];
        float2 o2;
        o2.x = fmaf(dn, ax + g.x, b2[0]);
        o2.y = fmaf(dn, ay + g.y, b2[1]);
        ((float2*)out)[n] = o2;
    }
}

// ======================= fallback (atomic scatter) kernels ==================

__global__ void k_deg_f(const int* __restrict__ dst, int* __restrict__ deg) {
    int i = blockIdx.x * blockDim.x + threadIdx.x;
    if (i < EE) atomicAdd(&deg[dst[i]], 1);
}
__global__ void k_dinv_f(const int* __restrict__ deg, float* __restrict__ dinv) {
    int n = blockIdx.x * blockDim.x + threadIdx.x;
    if (n < NN) dinv[n] = rsqrtf((float)(deg[n] + 1));
}
__global__ void k_xw_f(const float* __restrict__ x, const float* __restrict__ W1,
                       const float* __restrict__ dinv, float* __restrict__ g1) {
    __shared__ float Ws[INC * HIDC];
    for (int j = threadIdx.x; j < INC * HIDC; j += 256) Ws[j] = W1[j];
    __syncthreads();
    int n = blockIdx.x * 256 + threadIdx.x;
    if (n >= NN) return;
    const float4* xr = (const float4*)(x + (size_t)n * INC);
    float acc[HIDC];
#pragma unroll
    for (int c = 0; c < HIDC; ++c) acc[c] = 0.f;
    for (int k4 = 0; k4 < INC / 4; ++k4) {
        float4 xv = xr[k4];
        const float* w0 = &Ws[(k4 * 4) * HIDC];
        float xs[4] = {xv.x, xv.y, xv.z, xv.w};
#pragma unroll
        for (int j = 0; j < 4; ++j)
#pragma unroll
            for (int c = 0; c < HIDC; ++c) acc[c] += xs[j] * w0[j * HIDC + c];
    }
    float dn = dinv[n];
#pragma unroll
    for (int c = 0; c < HIDC; ++c) g1[(size_t)n * HIDC + c] = dn * acc[c];
}
__global__ void k_scatter1_f(const int* __restrict__ src, const int* __restrict__ dst,
                             const float* __restrict__ g1, float* __restrict__ acc1) {
    int i = blockIdx.x * blockDim.x + threadIdx.x;
    if (i >= EE * 4) return;
    int e = i >> 2, q = i & 3;
    float4 v = ((const float4*)g1)[src[e] * 4 + q];
    float* p = acc1 + (size_t)dst[e] * HIDC + q * 4;
    unsafeAtomicAdd(p + 0, v.x); unsafeAtomicAdd(p + 1, v.y);
    unsafeAtomicAdd(p + 2, v.z); unsafeAtomicAdd(p + 3, v.w);
}
__global__ void k_l2_f(const float* __restrict__ g1, const float* __restrict__ acc1,
                       const float* __restrict__ dinv, const float* __restrict__ b1,
                       const float* __restrict__ W2, float* __restrict__ g2) {
    int n = blockIdx.x * blockDim.x + threadIdx.x;
    if (n >= NN) return;
    float dn = dinv[n];
    float h[HIDC];
#pragma unroll
    for (int c = 0; c < HIDC; ++c)
        h[c] = fmaxf(dn * (acc1[(size_t)n * HIDC + c] + g1[(size_t)n * HIDC + c]) + b1[c], 0.f);
    float o0 = 0.f, o1 = 0.f;
#pragma unroll
    for (int c = 0; c < HIDC; ++c) { o0 += h[c] * W2[c * 2]; o1 += h[c] * W2[c * 2 + 1]; }
    g2[(size_t)n * 2] = dn * o0; g2[(size_t)n * 2 + 1] = dn * o1;
}
__global__ void k_scatter2_f(const int* __restrict__ src, const int* __restrict__ dst,
                             const float* __restrict__ g2, float* __restrict__ acc2) {
    int e = blockIdx.x * blockDim.x + threadIdx.x;
    if (e >= EE) return;
    float2 v = ((const float2*)g2)[src[e]];
    unsafeAtomicAdd(&acc2[(size_t)dst[e] * 2], v.x);
    unsafeAtomicAdd(&acc2[(size_t)dst[e] * 2 + 1], v.y);
}
__global__ void k_final_f(const float* __restrict__ g2, const float* __restrict__ acc2,
                          const float* __restrict__ dinv, const float* __restrict__ b2,
                          float* __restrict__ out) {
    int n = blockIdx.x * blockDim.x + threadIdx.x;
    if (n >= NN) return;
    float dn = dinv[n];
    float2 a = ((const float2*)acc2)[n];
    float2 g = ((const float2*)g2)[n];
    float2 o;
    o.x = dn * (a.x + g.x) + b2[0];
    o.y = dn * (a.y + g.y) + b2[1];
    ((float2*)out)[n] = o;
}

// ======================= launch =============================================

extern "C" void kernel_launch(void* const* d_in, const int* in_sizes, int n_in,
                              void* d_out, int out_size, void* d_ws, size_t ws_size,
                              hipStream_t stream) {
    const float* x  = (const float*)d_in[0];
    const int*   ei = (const int*)d_in[1];     // [2, E] flat: src then dst
    const float* W1 = (const float*)d_in[2];
    const float* b1 = (const float*)d_in[3];
    const float* W2 = (const float*)d_in[4];
    const float* b2 = (const float*)d_in[5];
    float* out = (float*)d_out;

    const int* src = ei;
    const int* dst = ei + EE;
    const int B = 256;

    // CSR-path workspace (4 B elements), total ~40.81 MB:
    //   tile_counts [0, NT)
    //   tile_base   [NT, 2NT)
    //   tile_cursor [2NT, 3NT)
    //   brec/csr    [3NT, 3NT+E)
    //   nstart      [.., +N+1)
    //   g1          [.., +16N)
    //   g2          [.., +2N)
    size_t need = ((size_t)3 * NT + EE + (size_t)(NN + 1) + (size_t)18 * NN) * 4;
    if (ws_size >= need) {
        int* ws          = (int*)d_ws;
        int* tile_counts = ws;
        int* tile_base   = ws + NT;
        int* tile_cursor = ws + 2 * NT;
        int* brec        = ws + 3 * NT;          // becomes node-sorted CSR
        int* nstart      = ws + 3 * NT + EE;
        float* g1        = (float*)(nstart + NN + 1);
        float* g2        = g1 + (size_t)NN * HIDC;

        hipMemsetAsync(tile_counts, 0, (size_t)NT * 4, stream);

        k_hist  <<<NBE, 256, 0, stream>>>(dst, tile_counts);
        k_scan  <<<1, 1024, 0, stream>>>(tile_counts, tile_base, tile_cursor, nstart);
        k_bplace<<<NBE, 256, 0, stream>>>(src, dst, tile_cursor, brec);
        k_sortt <<<NT, 256, 0, stream>>>(brec, tile_base, tile_counts, nstart);
        k_xw    <<<(NN + 255) / 256, 256, 0, stream>>>(x, W1, nstart, g1);
        k_agg1n <<<(NN * 16 + 255) / 256, 256, 0, stream>>>(brec, nstart, g1, b1, W2, g2);
        k_agg2n <<<(NN * 8 + 255) / 256, 256, 0, stream>>>(brec, nstart, g2, b2, out);
        return;
    }

    // -------- fallback: atomic-scatter path (needs 38N floats ~ 30.4 MB) ----
    char* wsb = (char*)d_ws;
    int*   deg  = (int*)wsb;
    float* acc1 = (float*)(wsb + (size_t)NN * 4);
    float* acc2 = (float*)(wsb + (size_t)17 * NN * 4);
    float* dinv = (float*)(wsb + (size_t)19 * NN * 4);
    float* g1   = (float*)(wsb + (size_t)20 * NN * 4);
    float* g2   = (float*)(wsb + (size_t)36 * NN * 4);

    hipMemsetAsync(d_ws, 0, (size_t)19 * NN * 4, stream);

    int gN = (NN + B - 1) / B, gE = (EE + B - 1) / B, gE4 = (EE * 4 + B - 1) / B;
    k_deg_f     <<<gE, B, 0, stream>>>(dst, deg);
    k_dinv_f    <<<gN, B, 0, stream>>>(deg, dinv);
    k_xw_f      <<<gN, B, 0, stream>>>(x, W1, dinv, g1);
    k_scatter1_f<<<gE4, B, 0, stream>>>(src, dst, g1, acc1);
    k_l2_f      <<<gN, B, 0, stream>>>(g1, acc1, dinv, b1, W2, g2);
    k_scatter2_f<<<gE, B, 0, stream>>>(src, dst, g2, acc2);
    k_final_f   <<<gN, B, 0, stream>>>(g2, acc2, dinv, b2, out);
}

// Round 7
// 509.583 us; speedup vs baseline: 4.5700x; 1.1363x over previous
//
#include <hip/hip_runtime.h>
#include <hip/hip_fp16.h>

#define NN   200000
#define EE   6400000
#define INC  128
#define HIDC 16
#define OUTC 2

#define TN     256                 // nodes per dst tile
#define TSHIFT 8
#define TMASK  (TN - 1)
#define NT     782                 // ceil(NN / TN)
#define CHUNK  8192                // edges per hist/place block
#define NBE    782                 // ceil(EE / CHUNK)
#define SCAP   10240               // per-tile record capacity (mean 8184, +22 sigma)

// ---------------- per-block tile histogram -> bcnt + tile_counts ------------
__global__ __launch_bounds__(256) void k_hist2(const int* __restrict__ dst,
                                               int* __restrict__ bcnt,
                                               int* __restrict__ tile_counts) {
    __shared__ int h[NT];
    for (int t = threadIdx.x; t < NT; t += 256) h[t] = 0;
    __syncthreads();
    int base = blockIdx.x * CHUNK;
    if (base + CHUNK <= EE) {
        for (int i = threadIdx.x; i < CHUNK; i += 1024) {
            int d0 = dst[base + i];
            int d1 = dst[base + i + 256];
            int d2 = dst[base + i + 512];
            int d3 = dst[base + i + 768];
            atomicAdd(&h[d0 >> TSHIFT], 1);
            atomicAdd(&h[d1 >> TSHIFT], 1);
            atomicAdd(&h[d2 >> TSHIFT], 1);
            atomicAdd(&h[d3 >> TSHIFT], 1);
        }
    } else {
        for (int i = threadIdx.x; i < CHUNK; i += 256) {
            int e = base + i;
            if (e < EE) atomicAdd(&h[dst[e] >> TSHIFT], 1);
        }
    }
    __syncthreads();
    int* row = bcnt + (size_t)blockIdx.x * NT;
    for (int t = threadIdx.x; t < NT; t += 256) {
        int c = h[t];
        row[t] = c;
        if (c) atomicAdd(&tile_counts[t], c);
    }
}

// ---------------- exclusive scan of tile counts (single block) --------------
__global__ __launch_bounds__(1024) void k_scan(const int* __restrict__ tile_counts,
                                               int* __restrict__ tile_base,
                                               int* __restrict__ nstart) {
    __shared__ int tmp[1024];
    int t = threadIdx.x;
    int v = (t < NT) ? tile_counts[t] : 0;
    tmp[t] = v;
    __syncthreads();
    for (int o = 1; o < 1024; o <<= 1) {
        int u = (t >= o) ? tmp[t - o] : 0;
        __syncthreads();
        tmp[t] += u;
        __syncthreads();
    }
    if (t < NT) tile_base[t] = tmp[t] - v;
    if (t == 0) nstart[NN] = EE;               // sentinel for deg of last node
}

// ---------------- per-(block,tile) cursors: scan bcnt columns ---------------
// one block per tile; thread b owns source-block b.
__global__ __launch_bounds__(1024) void k_scan2(const int* __restrict__ bcnt,
                                                const int* __restrict__ tile_base,
                                                int* __restrict__ lcur) {
    __shared__ int tmp[1024];
    int t = blockIdx.x;
    int b = threadIdx.x;
    int v = (b < NBE) ? bcnt[(size_t)b * NT + t] : 0;
    tmp[b] = v;
    __syncthreads();
    for (int o = 1; o < 1024; o <<= 1) {
        int u = (b >= o) ? tmp[b - o] : 0;
        __syncthreads();
        tmp[b] += u;
        __syncthreads();
    }
    if (b < NBE) lcur[(size_t)b * NT + t] = tile_base[t] + tmp[b] - v;
}

// ---------------- place edges into tile buckets (1 LDS atomic/edge) ---------
// record = (src << 8) | (dst & 255)
__global__ __launch_bounds__(256) void k_bplace2(const int* __restrict__ src,
                                                 const int* __restrict__ dst,
                                                 const int* __restrict__ lcur,
                                                 int* __restrict__ brec) {
    __shared__ int cur[NT];
    const int* row = lcur + (size_t)blockIdx.x * NT;
    for (int t = threadIdx.x; t < NT; t += 256) cur[t] = row[t];
    __syncthreads();
    int base = blockIdx.x * CHUNK;
    if (base + CHUNK <= EE) {
        for (int i = threadIdx.x; i < CHUNK; i += 1024) {
            int e = base + i;
            int d0 = dst[e], d1 = dst[e + 256], d2 = dst[e + 512], d3 = dst[e + 768];
            int s0 = src[e], s1 = src[e + 256], s2 = src[e + 512], s3 = src[e + 768];
            int p0 = atomicAdd(&cur[d0 >> TSHIFT], 1);
            int p1 = atomicAdd(&cur[d1 >> TSHIFT], 1);
            int p2 = atomicAdd(&cur[d2 >> TSHIFT], 1);
            int p3 = atomicAdd(&cur[d3 >> TSHIFT], 1);
            brec[p0] = (s0 << 8) | (d0 & TMASK);
            brec[p1] = (s1 << 8) | (d1 & TMASK);
            brec[p2] = (s2 << 8) | (d2 & TMASK);
            brec[p3] = (s3 << 8) | (d3 & TMASK);
        }
    } else {
        for (int i = threadIdx.x; i < CHUNK; i += 256) {
            int e = base + i;
            if (e < EE) {
                int d = dst[e], s = src[e];
                int pos = atomicAdd(&cur[d >> TSHIFT], 1);
                brec[pos] = (s << 8) | (d & TMASK);
            }
        }
    }
}

// ---------------- per-tile counting sort -> node-sorted CSR (in place) ------
__global__ __launch_bounds__(256) void k_sortt(int* __restrict__ brec,
                                               const int* __restrict__ tile_base,
                                               const int* __restrict__ tile_counts,
                                               int* __restrict__ nstart) {
    __shared__ int rec[SCAP];                  // 40 KB
    __shared__ int hist[TN];
    __shared__ int scn[TN];
    __shared__ int cur[TN];
    int t = blockIdx.x;
    int s0 = tile_base[t];
    int cnt = tile_counts[t];
    if (cnt > SCAP) cnt = SCAP;                // deterministic input: never hit
    if (threadIdx.x < TN) hist[threadIdx.x] = 0;
    __syncthreads();
    for (int i = threadIdx.x; i < cnt; i += 256) {
        int r = brec[s0 + i];
        rec[i] = r;
        atomicAdd(&hist[r & TMASK], 1);
    }
    __syncthreads();
    if (threadIdx.x < TN) scn[threadIdx.x] = hist[threadIdx.x];
    __syncthreads();
    for (int o = 1; o < TN; o <<= 1) {
        int u = (threadIdx.x >= o && threadIdx.x < TN) ? scn[threadIdx.x - o] : 0;
        __syncthreads();
        if (threadIdx.x < TN) scn[threadIdx.x] += u;
        __syncthreads();
    }
    if (threadIdx.x < TN) {
        int ex = scn[threadIdx.x] - hist[threadIdx.x];
        cur[threadIdx.x] = ex;
        int node = t * TN + threadIdx.x;
        if (node < NN) nstart[node] = s0 + ex;
    }
    __syncthreads();
    for (int i = threadIdx.x; i < cnt; i += 256) {
        int r = rec[i];
        int pos = atomicAdd(&cur[r & TMASK], 1);
        brec[s0 + pos] = r >> 8;               // store src id, node-sorted
    }
}

// ---------------- g1 = dinv * (x @ W1), stored fp16 -------------------------
__global__ __launch_bounds__(256) void k_xw(const float* __restrict__ x,
                                            const float* __restrict__ W1,
                                            const int* __restrict__ nstart,
                                            __half2* __restrict__ g1) {
    __shared__ float Ws[INC * HIDC];           // 8 KB
    for (int j = threadIdx.x; j < INC * HIDC; j += 256) Ws[j] = W1[j];
    __syncthreads();
    int n = blockIdx.x * 256 + threadIdx.x;
    if (n >= NN) return;
    const float4* xr = (const float4*)(x + (size_t)n * INC);
    float acc[HIDC];
#pragma unroll
    for (int c = 0; c < HIDC; ++c) acc[c] = 0.f;
    for (int k4 = 0; k4 < INC / 4; ++k4) {
        float4 xv = xr[k4];
        const float* w0 = &Ws[(k4 * 4) * HIDC];
        float xs[4] = {xv.x, xv.y, xv.z, xv.w};
#pragma unroll
        for (int j = 0; j < 4; ++j) {
#pragma unroll
            for (int c = 0; c < HIDC; ++c) acc[c] += xs[j] * w0[j * HIDC + c];
        }
    }
    float dn = rsqrtf((float)(nstart[n + 1] - nstart[n] + 1));   // +1 self-loop
    union { __half2 h[8]; float4 f[2]; } u;
#pragma unroll
    for (int q = 0; q < 8; ++q)
        u.h[q] = __floats2half2_rn(dn * acc[2 * q], dn * acc[2 * q + 1]);
    float4* gp = (float4*)(g1 + (size_t)n * 8);
    gp[0] = u.f[0];
    gp[1] = u.f[1];
}

// ---------------- layer-1 gather + fused MLP (fp16 rows, no atomics) --------
// 8 lanes per node, lane owns channels {2c, 2c+1}; 32 B coalesced row/edge.
__global__ __launch_bounds__(256) void k_agg1n(const int* __restrict__ csr,
                                               const int* __restrict__ nstart,
                                               const __half2* __restrict__ g1,
                                               const float* __restrict__ b1,
                                               const float* __restrict__ W2,
                                               float* __restrict__ g2) {
    int lane = threadIdx.x & 7;
    int n = (blockIdx.x * 256 + threadIdx.x) >> 3;
    if (n >= NN) return;
    int rs = nstart[n], re = nstart[n + 1];
    float dn = rsqrtf((float)(re - rs + 1));
    float2 s = __half22float2(g1[(size_t)n * 8 + lane]);   // self-loop
    float ax = s.x, ay = s.y;
    int i = rs;
    for (; i + 4 <= re; i += 4) {              // 4 row-loads in flight
        int s0 = csr[i], s1 = csr[i + 1], s2 = csr[i + 2], s3 = csr[i + 3];
        float2 f0 = __half22float2(g1[(size_t)s0 * 8 + lane]);
        float2 f1 = __half22float2(g1[(size_t)s1 * 8 + lane]);
        float2 f2 = __half22float2(g1[(size_t)s2 * 8 + lane]);
        float2 f3 = __half22float2(g1[(size_t)s3 * 8 + lane]);
        ax += f0.x + f1.x + f2.x + f3.x;
        ay += f0.y + f1.y + f2.y + f3.y;
    }
    for (; i < re; ++i) {
        float2 f = __half22float2(g1[(size_t)csr[i] * 8 + lane]);
        ax += f.x; ay += f.y;
    }
    float h0 = fmaxf(fmaf(dn, ax, b1[2 * lane]), 0.f);
    float h1 = fmaxf(fmaf(dn, ay, b1[2 * lane + 1]), 0.f);
    float p0 = h0 * W2[(2 * lane) * OUTC + 0] + h1 * W2[(2 * lane + 1) * OUTC + 0];
    float p1 = h0 * W2[(2 * lane) * OUTC + 1] + h1 * W2[(2 * lane + 1) * OUTC + 1];
#pragma unroll
    for (int o = 4; o; o >>= 1) {
        p0 += __shfl_xor(p0, o, 8);
        p1 += __shfl_xor(p1, o, 8);
    }
    if (lane == 0) {
        float2 v; v.x = dn * p0; v.y = dn * p1;
        ((float2*)g2)[n] = v;
    }
}

// ---------------- layer-2 gather + final epilogue (no atomics) --------------
__global__ __launch_bounds__(256) void k_agg2n(const int* __restrict__ csr,
                                               const int* __restrict__ nstart,
                                               const float* __restrict__ g2,
                                               const float* __restrict__ b2,
                                               float* __restrict__ out) {
    int lane = threadIdx.x & 7;
    int n = (blockIdx.x * 256 + threadIdx.x) >> 3;
    if (n >= NN) return;
    int rs = nstart[n], re = nstart[n + 1];
    float dn = rsqrtf((float)(re - rs + 1));
    float ax = 0.f, ay = 0.f;
    for (int i = rs + lane; i < re; i += 8) {
        float2 v = ((const float2*)g2)[csr[i]];
        ax += v.x; ay += v.y;
    }
#pragma unroll
    for (int o = 4; o; o >>= 1) {
        ax += __shfl_xor(ax, o, 8);
        ay += __shfl_xor(ay, o, 8);
    }
    if (lane == 0) {
        float2 g = ((const float2*)g2)[n];
        float2 o2;
        o2.x = fmaf(dn, ax + g.x, b2[0]);
        o2.y = fmaf(dn, ay + g.y, b2[1]);
        ((float2*)out)[n] = o2;
    }
}

// ======================= fallback (atomic scatter) kernels ==================

__global__ void k_deg_f(const int* __restrict__ dst, int* __restrict__ deg) {
    int i = blockIdx.x * blockDim.x + threadIdx.x;
    if (i < EE) atomicAdd(&deg[dst[i]], 1);
}
__global__ void k_dinv_f(const int* __restrict__ deg, float* __restrict__ dinv) {
    int n = blockIdx.x * blockDim.x + threadIdx.x;
    if (n < NN) dinv[n] = rsqrtf((float)(deg[n] + 1));
}
__global__ void k_xw_f(const float* __restrict__ x, const float* __restrict__ W1,
                       const float* __restrict__ dinv, float* __restrict__ g1) {
    __shared__ float Ws[INC * HIDC];
    for (int j = threadIdx.x; j < INC * HIDC; j += 256) Ws[j] = W1[j];
    __syncthreads();
    int n = blockIdx.x * 256 + threadIdx.x;
    if (n >= NN) return;
    const float4* xr = (const float4*)(x + (size_t)n * INC);
    float acc[HIDC];
#pragma unroll
    for (int c = 0; c < HIDC; ++c) acc[c] = 0.f;
    for (int k4 = 0; k4 < INC / 4; ++k4) {
        float4 xv = xr[k4];
        const float* w0 = &Ws[(k4 * 4) * HIDC];
        float xs[4] = {xv.x, xv.y, xv.z, xv.w};
#pragma unroll
        for (int j = 0; j < 4; ++j)
#pragma unroll
            for (int c = 0; c < HIDC; ++c) acc[c] += xs[j] * w0[j * HIDC + c];
    }
    float dn = dinv[n];
#pragma unroll
    for (int c = 0; c < HIDC; ++c) g1[(size_t)n * HIDC + c] = dn * acc[c];
}
__global__ void k_scatter1_f(const int* __restrict__ src, const int* __restrict__ dst,
                             const float* __restrict__ g1, float* __restrict__ acc1) {
    int i = blockIdx.x * blockDim.x + threadIdx.x;
    if (i >= EE * 4) return;
    int e = i >> 2, q = i & 3;
    float4 v = ((const float4*)g1)[src[e] * 4 + q];
    float* p = acc1 + (size_t)dst[e] * HIDC + q * 4;
    unsafeAtomicAdd(p + 0, v.x); unsafeAtomicAdd(p + 1, v.y);
    unsafeAtomicAdd(p + 2, v.z); unsafeAtomicAdd(p + 3, v.w);
}
__global__ void k_l2_f(const float* __restrict__ g1, const float* __restrict__ acc1,
                       const float* __restrict__ dinv, const float* __restrict__ b1,
                       const float* __restrict__ W2, float* __restrict__ g2) {
    int n = blockIdx.x * blockDim.x + threadIdx.x;
    if (n >= NN) return;
    float dn = dinv[n];
    float h[HIDC];
#pragma unroll
    for (int c = 0; c < HIDC; ++c)
        h[c] = fmaxf(dn * (acc1[(size_t)n * HIDC + c] + g1[(size_t)n * HIDC + c]) + b1[c], 0.f);
    float o0 = 0.f, o1 = 0.f;
#pragma unroll
    for (int c = 0; c < HIDC; ++c) { o0 += h[c] * W2[c * 2]; o1 += h[c] * W2[c * 2 + 1]; }
    g2[(size_t)n * 2] = dn * o0; g2[(size_t)n * 2 + 1] = dn * o1;
}
__global__ void k_scatter2_f(const int* __restrict__ src, const int* __restrict__ dst,
                             const float* __restrict__ g2, float* __restrict__ acc2) {
    int e = blockIdx.x * blockDim.x + threadIdx.x;
    if (e >= EE) return;
    float2 v = ((const float2*)g2)[src[e]];
    unsafeAtomicAdd(&acc2[(size_t)dst[e] * 2], v.x);
    unsafeAtomicAdd(&acc2[(size_t)dst[e] * 2 + 1], v.y);
}
__global__ void k_final_f(const float* __restrict__ g2, const float* __restrict__ acc2,
                          const float* __restrict__ dinv, const float* __restrict__ b2,
                          float* __restrict__ out) {
    int n = blockIdx.x * blockDim.x + threadIdx.x;
    if (n >= NN) return;
    float dn = dinv[n];
    float2 a = ((const float2*)acc2)[n];
    float2 g = ((const float2*)g2)[n];
    float2 o;
    o.x = dn * (a.x + g.x) + b2[0];
    o.y = dn * (a.y + g.y) + b2[1];
    ((float2*)out)[n] = o;
}

// ======================= launch =============================================

extern "C" void kernel_launch(void* const* d_in, const int* in_sizes, int n_in,
                              void* d_out, int out_size, void* d_ws, size_t ws_size,
                              hipStream_t stream) {
    const float* x  = (const float*)d_in[0];
    const int*   ei = (const int*)d_in[1];     // [2, E] flat: src then dst
    const float* W1 = (const float*)d_in[2];
    const float* b1 = (const float*)d_in[3];
    const float* W2 = (const float*)d_in[4];
    const float* b2 = (const float*)d_in[5];
    float* out = (float*)d_out;

    const int* src = ei;
    const int* dst = ei + EE;
    const int B = 256;

    // CSR-path workspace (4 B elements), total ~39.3 MB:
    //   tile_counts [0, NT)
    //   tile_base   [NT, 2NT)
    //   bcnt        [2NT, 2NT + NBE*NT)
    //   lcur        [.., + NBE*NT)
    //   brec/csr    [.., + E)
    //   nstart      [.., + N+1)
    //   g1 (fp16)   [.., + 8N)   16 halves/row
    //   g2 (fp32)   [.., + 2N)
    size_t need = ((size_t)2 * NT + (size_t)2 * NBE * NT + EE +
                   (size_t)(NN + 1) + (size_t)8 * NN + (size_t)2 * NN) * 4;
    if (ws_size >= need) {
        int* ws          = (int*)d_ws;
        int* tile_counts = ws;
        int* tile_base   = ws + NT;
        int* bcnt        = ws + 2 * NT;
        int* lcur        = bcnt + (size_t)NBE * NT;
        int* brec        = lcur + (size_t)NBE * NT;   // becomes node-sorted CSR
        int* nstart      = brec + EE;
        __half2* g1      = (__half2*)(nstart + NN + 1);
        float* g2        = (float*)((int*)(nstart + NN + 1) + (size_t)8 * NN);

        hipMemsetAsync(tile_counts, 0, (size_t)NT * 4, stream);

        k_hist2  <<<NBE, 256, 0, stream>>>(dst, bcnt, tile_counts);
        k_scan   <<<1, 1024, 0, stream>>>(tile_counts, tile_base, nstart);
        k_scan2  <<<NT, 1024, 0, stream>>>(bcnt, tile_base, lcur);
        k_bplace2<<<NBE, 256, 0, stream>>>(src, dst, lcur, brec);
        k_sortt  <<<NT, 256, 0, stream>>>(brec, tile_base, tile_counts, nstart);
        k_xw     <<<(NN + 255) / 256, 256, 0, stream>>>(x, W1, nstart, g1);
        k_agg1n  <<<(NN * 8 + 255) / 256, 256, 0, stream>>>(brec, nstart, g1, b1, W2, g2);
        k_agg2n  <<<(NN * 8 + 255) / 256, 256, 0, stream>>>(brec, nstart, g2, b2, out);
        return;
    }

    // -------- fallback: atomic-scatter path (needs 38N floats ~ 30.4 MB) ----
    char* wsb = (char*)d_ws;
    int*   deg  = (int*)wsb;
    float* acc1 = (float*)(wsb + (size_t)NN * 4);
    float* acc2 = (float*)(wsb + (size_t)17 * NN * 4);
    float* dinv = (float*)(wsb + (size_t)19 * NN * 4);
    float* g1   = (float*)(wsb + (size_t)20 * NN * 4);
    float* g2   = (float*)(wsb + (size_t)36 * NN * 4);

    hipMemsetAsync(d_ws, 0, (size_t)19 * NN * 4, stream);

    int gN = (NN + B - 1) / B, gE = (EE + B - 1) / B, gE4 = (EE * 4 + B - 1) / B;
    k_deg_f     <<<gE, B, 0, stream>>>(dst, deg);
    k_dinv_f    <<<gN, B, 0, stream>>>(deg, dinv);
    k_xw_f      <<<gN, B, 0, stream>>>(x, W1, dinv, g1);
    k_scatter1_f<<<gE4, B, 0, stream>>>(src, dst, g1, acc1);
    k_l2_f      <<<gN, B, 0, stream>>>(g1, acc1, dinv, b1, W2, g2);
    k_scatter2_f<<<gE, B, 0, stream>>>(src, dst, g2, acc2);
    k_final_f   <<<gN, B, 0, stream>>>(g2, acc2, dinv, b2, out);
}